// Round 1
// baseline (1089.992 us; speedup 1.0000x reference)
//
#include <hip/hip_runtime.h>
#include <math.h>

#define NB 16      // batch
#define NC 3       // obs channels
#define NN 3000    // nodes
#define NT 50      // time
#define NE 96000   // edges
#define NR 3       // relations
#define NS 500     // selected stocks
#define NF 43      // feature dim

// workspace layout (floats)
#define X_OFF    0
#define H1_OFF   (X_OFF  + NB*NN*NF)
#define H2_OFF   (H1_OFF + NB*NN*NF)
#define Y_OFF    (H2_OFF + NB*NN*NF)
#define CNT_OFF  (Y_OFF  + NR*NB*NN*NF)
#define ICNT_OFF (CNT_OFF + NR*NN)

// ---------------- edge-count kernels ----------------
__global__ __launch_bounds__(256) void k_cnt(const int* __restrict__ ei,
                                             const int* __restrict__ et,
                                             float* __restrict__ cnt) {
    int e = blockIdx.x * 256 + threadIdx.x;
    if (e >= NE) return;
    atomicAdd(&cnt[et[e] * NN + ei[NE + e]], 1.0f);
}

__global__ __launch_bounds__(256) void k_icnt(const float* __restrict__ cnt,
                                              float* __restrict__ icnt) {
    int i = blockIdx.x * 256 + threadIdx.x;
    if (i >= NR * NN) return;
    icnt[i] = 1.0f / fmaxf(cnt[i], 1.0f);
}

// ---------------- temporal feature kernel ----------------
// one thread per (b,n): short conv stack (k=3 then k=48), mid conv stack
// (k=21 then k=30), long max-pool. Writes x[b*NN+n][0..42].
__global__ __launch_bounds__(256, 1) void k_temporal(
    const float* __restrict__ obs,
    const float* __restrict__ ws1, const float* __restrict__ bs1,
    const float* __restrict__ ws2, const float* __restrict__ bs2,
    const float* __restrict__ wm1, const float* __restrict__ bm1,
    const float* __restrict__ wm2, const float* __restrict__ bm2,
    float* __restrict__ x)
{
    int idx = blockIdx.x * 256 + threadIdx.x;
    if (idx >= NB * NN) return;
    int b = idx / NN, n = idx - b * NN;

    float row[NC][NT];
    #pragma unroll
    for (int c = 0; c < NC; ++c) {
        const float2* p2 = (const float2*)(obs + ((size_t)(b * NC + c) * NN + n) * NT);
        #pragma unroll
        for (int t = 0; t < NT / 2; ++t) {
            float2 u = p2[t];
            row[c][2 * t] = u.x; row[c][2 * t + 1] = u.y;
        }
    }

    float* xp = x + (size_t)idx * NF;

    // ---- short path: conv(1x3)->relu->conv(1x48)->relu ----
    {
        float acc2[20];
        #pragma unroll
        for (int o = 0; o < 20; ++o) acc2[o] = bs2[o];
        #pragma unroll
        for (int c = 0; c < 3; ++c) {
            float v[48];
            #pragma unroll
            for (int t = 0; t < 48; ++t) {
                float s = bs1[c];
                #pragma unroll
                for (int i = 0; i < 3; ++i)
                    #pragma unroll
                    for (int k = 0; k < 3; ++k)
                        s = fmaf(row[i][t + k], ws1[(c * 3 + i) * 3 + k], s);
                v[t] = fmaxf(s, 0.f);
            }
            #pragma unroll
            for (int o = 0; o < 20; ++o) {
                float a = 0.f;
                #pragma unroll
                for (int t = 0; t < 48; ++t)
                    a = fmaf(v[t], ws2[(o * 3 + c) * 48 + t], a);
                acc2[o] += a;
            }
        }
        #pragma unroll
        for (int o = 0; o < 20; ++o) xp[o] = fmaxf(acc2[o], 0.f);
    }

    // ---- mid path: conv(1x21)->relu->conv(1x30)->relu ----
    {
        float acc2[20];
        #pragma unroll
        for (int o = 0; o < 20; ++o) acc2[o] = bm2[o];
        #pragma unroll
        for (int c = 0; c < 3; ++c) {
            float v[30];
            #pragma unroll
            for (int t = 0; t < 30; ++t) {
                float s = bm1[c];
                #pragma unroll
                for (int i = 0; i < 3; ++i)
                    #pragma unroll
                    for (int k = 0; k < 21; ++k)
                        s = fmaf(row[i][t + k], wm1[(c * 3 + i) * 21 + k], s);
                v[t] = fmaxf(s, 0.f);
            }
            #pragma unroll
            for (int o = 0; o < 20; ++o) {
                float a = 0.f;
                #pragma unroll
                for (int t = 0; t < 30; ++t)
                    a = fmaf(v[t], wm2[(o * 3 + c) * 30 + t], a);
                acc2[o] += a;
            }
        }
        #pragma unroll
        for (int o = 0; o < 20; ++o) xp[20 + o] = fmaxf(acc2[o], 0.f);
    }

    // ---- long path: relu(max over t) ----
    #pragma unroll
    for (int c = 0; c < 3; ++c) {
        float m = row[c][0];
        #pragma unroll
        for (int t = 1; t < NT; ++t) m = fmaxf(m, row[c][t]);
        xp[40 + c] = fmaxf(m, 0.f);
    }
}

// ---------------- RGCN dense part ----------------
// thread per row: hout = (leaky?lrelu(xin):xin) @ root + bias ; y[r] = in @ rel[r]
__global__ __launch_bounds__(256) void k_gemm(
    const float* __restrict__ xin, const float* __restrict__ root,
    const float* __restrict__ rel, const float* __restrict__ bias,
    float* __restrict__ hout, float* __restrict__ y, int leaky)
{
    int idx = blockIdx.x * 256 + threadIdx.x;
    if (idx >= NB * NN) return;

    float v[NF];
    const float* xp = xin + (size_t)idx * NF;
    #pragma unroll
    for (int k = 0; k < NF; ++k) {
        float t = xp[k];
        v[k] = leaky ? (t >= 0.f ? t : 0.01f * t) : t;
    }

    float acc[NF];
    #pragma unroll
    for (int f = 0; f < NF; ++f) acc[f] = bias[f];
    for (int k = 0; k < NF; ++k) {
        float vk = v[k];
        const float* w = root + k * NF;
        #pragma unroll
        for (int f = 0; f < NF; ++f) acc[f] = fmaf(vk, w[f], acc[f]);
    }
    float* hp = hout + (size_t)idx * NF;
    #pragma unroll
    for (int f = 0; f < NF; ++f) hp[f] = acc[f];

    for (int r = 0; r < NR; ++r) {
        #pragma unroll
        for (int f = 0; f < NF; ++f) acc[f] = 0.f;
        const float* wr = rel + r * NF * NF;
        for (int k = 0; k < NF; ++k) {
            float vk = v[k];
            const float* w = wr + k * NF;
            #pragma unroll
            for (int f = 0; f < NF; ++f) acc[f] = fmaf(vk, w[f], acc[f]);
        }
        float* yp = y + ((size_t)r * NB * NN + idx) * NF;
        #pragma unroll
        for (int f = 0; f < NF; ++f) yp[f] = acc[f];
    }
}

// ---------------- edge scatter (mean fold into per-edge scale) ----------------
// thread per (e,b,f): h[b,dst,f] += y[type,b,src,f] * icnt[type,dst]
__global__ __launch_bounds__(256) void k_scatter(
    const float* __restrict__ y, const int* __restrict__ ei,
    const int* __restrict__ et, const float* __restrict__ icnt,
    float* __restrict__ h)
{
    int idx = blockIdx.x * 256 + threadIdx.x;
    if (idx >= NE * NB * NF) return;
    int f  = idx % NF;
    int eb = idx / NF;
    int b  = eb & (NB - 1);
    int e  = eb >> 4;
    int s  = ei[e];
    int d  = ei[NE + e];
    int t  = et[e];
    float ic  = icnt[t * NN + d];
    float val = y[(((size_t)t * NB + b) * NN + s) * NF + f] * ic;
    atomicAdd(&h[((size_t)b * NN + d) * NF + f], val);
}

// ---------------- epilogue: gather + 1x1 conv + softmax ----------------
__device__ inline float wred_max(float v) {
    #pragma unroll
    for (int o = 32; o > 0; o >>= 1) v = fmaxf(v, __shfl_down(v, o));
    return v;
}
__device__ inline float wred_sum(float v) {
    #pragma unroll
    for (int o = 32; o > 0; o >>= 1) v += __shfl_down(v, o);
    return v;
}

__global__ __launch_bounds__(512) void k_final(
    const float* __restrict__ x, const float* __restrict__ h2,
    const float* __restrict__ la, const int* __restrict__ nodes,
    const float* __restrict__ wf, const float* __restrict__ bf,
    float* __restrict__ out)
{
    __shared__ float sl[NS + 1];
    __shared__ float sred[8];
    __shared__ float sbc[2];
    int b = blockIdx.x, tid = threadIdx.x;

    if (tid < NS) {
        int node = nodes[tid];
        float acc = bf[0] + wf[0] * la[b * (NS + 1) + 1 + tid];
        const float* xp = x  + ((size_t)b * NN + node) * NF;
        const float* hp = h2 + ((size_t)b * NN + node) * NF;
        #pragma unroll
        for (int c = 0; c < NF; ++c) acc = fmaf(wf[1 + c], xp[c], acc);
        #pragma unroll
        for (int c = 0; c < NF; ++c) {
            float t = hp[c];
            t = t >= 0.f ? t : 0.01f * t;   // leaky relu on RGCN2 output
            acc = fmaf(wf[44 + c], t, acc);
        }
        sl[tid + 1] = acc;
    }
    if (tid == 0) sl[0] = 0.f;   // cash logit
    __syncthreads();

    float m = (tid < NS + 1) ? sl[tid] : -3.0e38f;
    m = wred_max(m);
    if ((tid & 63) == 0) sred[tid >> 6] = m;
    __syncthreads();
    if (tid == 0) {
        float mm = sred[0];
        #pragma unroll
        for (int i = 1; i < 8; ++i) mm = fmaxf(mm, sred[i]);
        sbc[0] = mm;
    }
    __syncthreads();
    float mx = sbc[0];
    float e = (tid < NS + 1) ? expf(sl[tid] - mx) : 0.f;
    float s = wred_sum(e);
    if ((tid & 63) == 0) sred[tid >> 6] = s;
    __syncthreads();
    if (tid == 0) {
        float t = 0.f;
        #pragma unroll
        for (int i = 0; i < 8; ++i) t += sred[i];
        sbc[1] = t;
    }
    __syncthreads();
    if (tid < NS + 1) out[(size_t)b * (NS + 1) + tid] = e / sbc[1];
}

extern "C" void kernel_launch(void* const* d_in, const int* in_sizes, int n_in,
                              void* d_out, int out_size, void* d_ws, size_t ws_size,
                              hipStream_t stream)
{
    const float* obs   = (const float*)d_in[0];
    const float* la    = (const float*)d_in[1];
    const int*   ei    = (const int*)d_in[2];
    const int*   et    = (const int*)d_in[3];
    const int*   nodes = (const int*)d_in[4];
    const float* ws1 = (const float*)d_in[5],  *bs1 = (const float*)d_in[6];
    const float* ws2 = (const float*)d_in[7],  *bs2 = (const float*)d_in[8];
    const float* wm1 = (const float*)d_in[9],  *bm1 = (const float*)d_in[10];
    const float* wm2 = (const float*)d_in[11], *bm2 = (const float*)d_in[12];
    const float* root1 = (const float*)d_in[13], *rel1 = (const float*)d_in[14], *bias1 = (const float*)d_in[15];
    const float* root2 = (const float*)d_in[16], *rel2 = (const float*)d_in[17], *bias2 = (const float*)d_in[18];
    const float* wf = (const float*)d_in[19], *bf = (const float*)d_in[20];

    float* wsp  = (float*)d_ws;
    float* x    = wsp + X_OFF;
    float* h1   = wsp + H1_OFF;
    float* h2   = wsp + H2_OFF;
    float* y    = wsp + Y_OFF;
    float* cnt  = wsp + CNT_OFF;
    float* icnt = wsp + ICNT_OFF;

    hipMemsetAsync(cnt, 0, NR * NN * sizeof(float), stream);
    k_cnt<<<(NE + 255) / 256, 256, 0, stream>>>(ei, et, cnt);
    k_icnt<<<(NR * NN + 255) / 256, 256, 0, stream>>>(cnt, icnt);

    k_temporal<<<(NB * NN + 255) / 256, 256, 0, stream>>>(
        obs, ws1, bs1, ws2, bs2, wm1, bm1, wm2, bm2, x);

    // RGCN layer 1 (input: x, no leaky on input)
    k_gemm<<<(NB * NN + 255) / 256, 256, 0, stream>>>(x, root1, rel1, bias1, h1, y, 0);
    k_scatter<<<(NE * NB * NF + 255) / 256, 256, 0, stream>>>(y, ei, et, icnt, h1);

    // RGCN layer 2 (input: leaky(h1))
    k_gemm<<<(NB * NN + 255) / 256, 256, 0, stream>>>(h1, root2, rel2, bias2, h2, y, 1);
    k_scatter<<<(NE * NB * NF + 255) / 256, 256, 0, stream>>>(y, ei, et, icnt, h2);

    k_final<<<NB, 512, 0, stream>>>(x, h2, la, nodes, wf, bf, (float*)d_out);
}

// Round 2
// 693.451 us; speedup vs baseline: 1.5718x; 1.5718x over previous
//
#include <hip/hip_runtime.h>
#include <math.h>

#define NB 16      // batch
#define NC 3       // obs channels
#define NN 3000    // nodes
#define NT 50      // time
#define NE 96000   // edges
#define NR 3       // relations
#define NS 500     // selected stocks
#define NF 43      // feature dim
#define NBKT (NR*NN)   // 9000 CSR buckets keyed (rel, dst)

// ---------------- workspace layout ----------------
// floats
#define X_OFF    0
#define H1_OFF   (X_OFF  + NB*NN*NF)
#define H2_OFF   (H1_OFF + NB*NN*NF)
#define ICNT_OFF (H2_OFF + NB*NN*NF)
// ints (after float region)
#define INT_BASE (ICNT_OFF + NBKT)
#define HIST_OFF  0
#define OFFS_OFF  (HIST_OFF + NBKT)        // NBKT+1 entries
#define CURS_OFF  (OFFS_OFF + NBKT + 1)
#define EBUF_OFF  (CURS_OFF + NBKT)

// ---------------- CSR build ----------------
__global__ __launch_bounds__(256) void k_hist(const int* __restrict__ ei,
                                              const int* __restrict__ et,
                                              int* __restrict__ hist) {
    int e = blockIdx.x * 256 + threadIdx.x;
    if (e >= NE) return;
    atomicAdd(&hist[et[e] * NN + ei[NE + e]], 1);
}

// single block of 1024: exclusive scan over 9000 bucket counts
__global__ __launch_bounds__(1024) void k_scan(const int* __restrict__ hist,
                                               int* __restrict__ off,
                                               int* __restrict__ cursor,
                                               float* __restrict__ icnt) {
    __shared__ int sp[1024];
    int t = threadIdx.x;
    int base = t * 9;
    int c[9]; int tot = 0;
    #pragma unroll
    for (int i = 0; i < 9; ++i) {
        int idx = base + i;
        c[i] = (idx < NBKT) ? hist[idx] : 0;
        tot += c[i];
    }
    sp[t] = tot;
    __syncthreads();
    for (int s = 1; s < 1024; s <<= 1) {
        int v = sp[t];
        int u = (t >= s) ? sp[t - s] : 0;
        __syncthreads();
        sp[t] = v + u;
        __syncthreads();
    }
    int pre = (t > 0) ? sp[t - 1] : 0;    // exclusive prefix
    #pragma unroll
    for (int i = 0; i < 9; ++i) {
        int idx = base + i;
        if (idx < NBKT) {
            off[idx] = pre;
            cursor[idx] = pre;
            icnt[idx] = 1.0f / fmaxf((float)c[i], 1.0f);
            pre += c[i];
        }
    }
    if (t == 1023) off[NBKT] = sp[1023];
}

__global__ __launch_bounds__(256) void k_fill(const int* __restrict__ ei,
                                              const int* __restrict__ et,
                                              int* __restrict__ cursor,
                                              int* __restrict__ ebuf) {
    int e = blockIdx.x * 256 + threadIdx.x;
    if (e >= NE) return;
    int bkt = et[e] * NN + ei[NE + e];
    int pos = atomicAdd(&cursor[bkt], 1);
    ebuf[pos] = ei[e];  // src
}

// ---------------- temporal feature kernel ----------------
__global__ __launch_bounds__(256, 1) void k_temporal(
    const float* __restrict__ obs,
    const float* __restrict__ ws1, const float* __restrict__ bs1,
    const float* __restrict__ ws2, const float* __restrict__ bs2,
    const float* __restrict__ wm1, const float* __restrict__ bm1,
    const float* __restrict__ wm2, const float* __restrict__ bm2,
    float* __restrict__ x)
{
    int idx = blockIdx.x * 256 + threadIdx.x;
    if (idx >= NB * NN) return;
    int b = idx / NN, n = idx - b * NN;

    float row[NC][NT];
    #pragma unroll
    for (int c = 0; c < NC; ++c) {
        const float2* p2 = (const float2*)(obs + ((size_t)(b * NC + c) * NN + n) * NT);
        #pragma unroll
        for (int t = 0; t < NT / 2; ++t) {
            float2 u = p2[t];
            row[c][2 * t] = u.x; row[c][2 * t + 1] = u.y;
        }
    }

    float* xp = x + (size_t)idx * NF;

    { // short: conv(1x3)->relu->conv(1x48)->relu
        float acc2[20];
        #pragma unroll
        for (int o = 0; o < 20; ++o) acc2[o] = bs2[o];
        #pragma unroll
        for (int c = 0; c < 3; ++c) {
            float v[48];
            #pragma unroll
            for (int t = 0; t < 48; ++t) {
                float s = bs1[c];
                #pragma unroll
                for (int i = 0; i < 3; ++i)
                    #pragma unroll
                    for (int k = 0; k < 3; ++k)
                        s = fmaf(row[i][t + k], ws1[(c * 3 + i) * 3 + k], s);
                v[t] = fmaxf(s, 0.f);
            }
            #pragma unroll
            for (int o = 0; o < 20; ++o) {
                float a = 0.f;
                #pragma unroll
                for (int t = 0; t < 48; ++t)
                    a = fmaf(v[t], ws2[(o * 3 + c) * 48 + t], a);
                acc2[o] += a;
            }
        }
        #pragma unroll
        for (int o = 0; o < 20; ++o) xp[o] = fmaxf(acc2[o], 0.f);
    }

    { // mid: conv(1x21)->relu->conv(1x30)->relu
        float acc2[20];
        #pragma unroll
        for (int o = 0; o < 20; ++o) acc2[o] = bm2[o];
        #pragma unroll
        for (int c = 0; c < 3; ++c) {
            float v[30];
            #pragma unroll
            for (int t = 0; t < 30; ++t) {
                float s = bm1[c];
                #pragma unroll
                for (int i = 0; i < 3; ++i)
                    #pragma unroll
                    for (int k = 0; k < 21; ++k)
                        s = fmaf(row[i][t + k], wm1[(c * 3 + i) * 21 + k], s);
                v[t] = fmaxf(s, 0.f);
            }
            #pragma unroll
            for (int o = 0; o < 20; ++o) {
                float a = 0.f;
                #pragma unroll
                for (int t = 0; t < 30; ++t)
                    a = fmaf(v[t], wm2[(o * 3 + c) * 30 + t], a);
                acc2[o] += a;
            }
        }
        #pragma unroll
        for (int o = 0; o < 20; ++o) xp[20 + o] = fmaxf(acc2[o], 0.f);
    }

    #pragma unroll
    for (int c = 0; c < 3; ++c) {
        float m = row[c][0];
        #pragma unroll
        for (int t = 1; t < NT; ++t) m = fmaxf(m, row[c][t]);
        xp[40 + c] = fmaxf(m, 0.f);
    }
}

// ---------------- fused RGCN layer (gather, no atomics) ----------------
// out[b,dst,:] = act(in)[b,dst,:]@root + bias
//              + sum_r icnt[r,dst] * (sum_{e in bucket(r,dst)} act(in)[b,src,:]) @ rel[r]
// wave per (b,dst); lane = output feature. Weights staged in LDS; z-vectors
// transposed through LDS. Each output row written exactly once.
__global__ __launch_bounds__(256) void k_agg(
    const float* __restrict__ in, const float* __restrict__ root,
    const float* __restrict__ rel, const float* __restrict__ bias,
    const float* __restrict__ icnt, const int* __restrict__ off,
    const int* __restrict__ ebuf, float* __restrict__ out, int leaky)
{
    __shared__ float sw[4 * NF * NF];      // root | rel0 | rel1 | rel2
    __shared__ float sz[4][4][NF + 1];     // per wave: in_row, z0, z1, z2

    int tid = threadIdx.x;
    for (int i = tid; i < NF * NF; i += 256) sw[i] = root[i];
    for (int i = tid; i < NR * NF * NF; i += 256) sw[NF * NF + i] = rel[i];
    __syncthreads();

    // b = blockIdx&15 so each XCD (blockIdx%8) sees only 2 batches -> L2-resident gather
    int b  = blockIdx.x & 15;
    int cb = blockIdx.x >> 4;              // node chunk [0,47)
    int wave = tid >> 6, lane = tid & 63;
    const float* inb = in + (size_t)b * NN * NF;

    for (int it = 0; it < 16; ++it) {
        int dst = cb * 64 + it * 4 + wave;
        bool valid = dst < NN;
        if (valid) {
            float inv = 0.f;
            float z0 = 0.f, z1 = 0.f, z2 = 0.f;
            if (lane < NF) {
                inv = inb[dst * NF + lane];
                if (leaky) inv = inv >= 0.f ? inv : 0.01f * inv;
            }
            #pragma unroll
            for (int r = 0; r < NR; ++r) {
                int bkt = r * NN + dst;
                int e0 = off[bkt], e1 = off[bkt + 1];
                float zr = 0.f;
                for (int e = e0; e < e1; ++e) {
                    int s = ebuf[e];                    // wave-uniform broadcast
                    if (lane < NF) {
                        float v = inb[s * NF + lane];   // coalesced row read
                        if (leaky) v = v >= 0.f ? v : 0.01f * v;
                        zr += v;
                    }
                }
                zr *= icnt[bkt];
                if (r == 0) z0 = zr; else if (r == 1) z1 = zr; else z2 = zr;
            }
            if (lane < NF) {
                sz[wave][0][lane] = inv;
                sz[wave][1][lane] = z0;
                sz[wave][2][lane] = z1;
                sz[wave][3][lane] = z2;
            }
        }
        __syncthreads();
        if (valid && lane < NF) {
            float acc = bias[lane];
            for (int f = 0; f < NF; ++f) {
                acc = fmaf(sz[wave][0][f], sw[f * NF + lane], acc);
                acc = fmaf(sz[wave][1][f], sw[(NF + f) * NF + lane], acc);
                acc = fmaf(sz[wave][2][f], sw[(2 * NF + f) * NF + lane], acc);
                acc = fmaf(sz[wave][3][f], sw[(3 * NF + f) * NF + lane], acc);
            }
            out[((size_t)b * NN + dst) * NF + lane] = acc;
        }
        __syncthreads();
    }
}

// ---------------- epilogue: gather + 1x1 conv + softmax ----------------
__device__ inline float wred_max(float v) {
    #pragma unroll
    for (int o = 32; o > 0; o >>= 1) v = fmaxf(v, __shfl_down(v, o));
    return v;
}
__device__ inline float wred_sum(float v) {
    #pragma unroll
    for (int o = 32; o > 0; o >>= 1) v += __shfl_down(v, o);
    return v;
}

__global__ __launch_bounds__(512) void k_final(
    const float* __restrict__ x, const float* __restrict__ h2,
    const float* __restrict__ la, const int* __restrict__ nodes,
    const float* __restrict__ wf, const float* __restrict__ bf,
    float* __restrict__ out)
{
    __shared__ float sl[NS + 1];
    __shared__ float sred[8];
    __shared__ float sbc[2];
    int b = blockIdx.x, tid = threadIdx.x;

    if (tid < NS) {
        int node = nodes[tid];
        float acc = bf[0] + wf[0] * la[b * (NS + 1) + 1 + tid];
        const float* xp = x  + ((size_t)b * NN + node) * NF;
        const float* hp = h2 + ((size_t)b * NN + node) * NF;
        #pragma unroll
        for (int c = 0; c < NF; ++c) acc = fmaf(wf[1 + c], xp[c], acc);
        #pragma unroll
        for (int c = 0; c < NF; ++c) {
            float t = hp[c];
            t = t >= 0.f ? t : 0.01f * t;   // leaky relu on RGCN2 output
            acc = fmaf(wf[44 + c], t, acc);
        }
        sl[tid + 1] = acc;
    }
    if (tid == 0) sl[0] = 0.f;   // cash logit
    __syncthreads();

    float m = (tid < NS + 1) ? sl[tid] : -3.0e38f;
    m = wred_max(m);
    if ((tid & 63) == 0) sred[tid >> 6] = m;
    __syncthreads();
    if (tid == 0) {
        float mm = sred[0];
        #pragma unroll
        for (int i = 1; i < 8; ++i) mm = fmaxf(mm, sred[i]);
        sbc[0] = mm;
    }
    __syncthreads();
    float mx = sbc[0];
    float e = (tid < NS + 1) ? expf(sl[tid] - mx) : 0.f;
    float s = wred_sum(e);
    if ((tid & 63) == 0) sred[tid >> 6] = s;
    __syncthreads();
    if (tid == 0) {
        float t = 0.f;
        #pragma unroll
        for (int i = 0; i < 8; ++i) t += sred[i];
        sbc[1] = t;
    }
    __syncthreads();
    if (tid < NS + 1) out[(size_t)b * (NS + 1) + tid] = e / sbc[1];
}

extern "C" void kernel_launch(void* const* d_in, const int* in_sizes, int n_in,
                              void* d_out, int out_size, void* d_ws, size_t ws_size,
                              hipStream_t stream)
{
    const float* obs   = (const float*)d_in[0];
    const float* la    = (const float*)d_in[1];
    const int*   ei    = (const int*)d_in[2];
    const int*   et    = (const int*)d_in[3];
    const int*   nodes = (const int*)d_in[4];
    const float* ws1 = (const float*)d_in[5],  *bs1 = (const float*)d_in[6];
    const float* ws2 = (const float*)d_in[7],  *bs2 = (const float*)d_in[8];
    const float* wm1 = (const float*)d_in[9],  *bm1 = (const float*)d_in[10];
    const float* wm2 = (const float*)d_in[11], *bm2 = (const float*)d_in[12];
    const float* root1 = (const float*)d_in[13], *rel1 = (const float*)d_in[14], *bias1 = (const float*)d_in[15];
    const float* root2 = (const float*)d_in[16], *rel2 = (const float*)d_in[17], *bias2 = (const float*)d_in[18];
    const float* wf = (const float*)d_in[19], *bf = (const float*)d_in[20];

    float* wsp  = (float*)d_ws;
    float* x    = wsp + X_OFF;
    float* h1   = wsp + H1_OFF;
    float* h2   = wsp + H2_OFF;
    float* icnt = wsp + ICNT_OFF;
    int*   ibase  = (int*)(wsp + INT_BASE);
    int*   hist   = ibase + HIST_OFF;
    int*   offs   = ibase + OFFS_OFF;
    int*   cursor = ibase + CURS_OFF;
    int*   ebuf   = ibase + EBUF_OFF;

    // CSR build (graph fixed across both layers)
    hipMemsetAsync(hist, 0, NBKT * sizeof(int), stream);
    k_hist<<<(NE + 255) / 256, 256, 0, stream>>>(ei, et, hist);
    k_scan<<<1, 1024, 0, stream>>>(hist, offs, cursor, icnt);
    k_fill<<<(NE + 255) / 256, 256, 0, stream>>>(ei, et, cursor, ebuf);

    k_temporal<<<(NB * NN + 255) / 256, 256, 0, stream>>>(
        obs, ws1, bs1, ws2, bs2, wm1, bm1, wm2, bm2, x);

    // RGCN layer 1: in = x (no input activation)
    k_agg<<<16 * 47, 256, 0, stream>>>(x, root1, rel1, bias1, icnt, offs, ebuf, h1, 0);
    // RGCN layer 2: in = leaky(h1)
    k_agg<<<16 * 47, 256, 0, stream>>>(h1, root2, rel2, bias2, icnt, offs, ebuf, h2, 1);

    k_final<<<NB, 512, 0, stream>>>(x, h2, la, nodes, wf, bf, (float*)d_out);
}

// Round 3
// 413.838 us; speedup vs baseline: 2.6339x; 1.6757x over previous
//
#include <hip/hip_runtime.h>
#include <math.h>

#define NB 16      // batch
#define NC 3       // obs channels
#define NN 3000    // nodes
#define NT 50      // time
#define NE 96000   // edges
#define NR 3       // relations
#define NS 500     // selected stocks
#define NF 43      // feature dim
#define NFP 44     // padded feature dim (16B-aligned rows)
#define NBKT (NR*NN)   // 9000 CSR buckets keyed (rel, dst)

// ---------------- workspace layout (floats, then ints) ----------------
#define X_OFF    0
#define H1_OFF   (X_OFF  + NB*NN*NF)
#define H2_OFF   (H1_OFF + NB*NN*NF)
#define Z_OFF    (H2_OFF + NB*NS*NF)
#define ICNT_OFF (Z_OFF  + NB*NN*NR*NFP)
#define INT_BASE (ICNT_OFF + NBKT)
#define HIST_OFF  0
#define OFFS_OFF  (HIST_OFF + NBKT)        // NBKT+1 entries
#define CURS_OFF  (OFFS_OFF + NBKT + 1)
#define EBUF_OFF  (CURS_OFF + NBKT)

// ---------------- CSR build ----------------
__global__ __launch_bounds__(256) void k_hist(const int* __restrict__ ei,
                                              const int* __restrict__ et,
                                              int* __restrict__ hist) {
    int e = blockIdx.x * 256 + threadIdx.x;
    if (e >= NE) return;
    atomicAdd(&hist[et[e] * NN + ei[NE + e]], 1);
}

__global__ __launch_bounds__(1024) void k_scan(const int* __restrict__ hist,
                                               int* __restrict__ off,
                                               int* __restrict__ cursor,
                                               float* __restrict__ icnt) {
    __shared__ int sp[1024];
    int t = threadIdx.x;
    int base = t * 9;
    int c[9]; int tot = 0;
    #pragma unroll
    for (int i = 0; i < 9; ++i) {
        int idx = base + i;
        c[i] = (idx < NBKT) ? hist[idx] : 0;
        tot += c[i];
    }
    sp[t] = tot;
    __syncthreads();
    for (int s = 1; s < 1024; s <<= 1) {
        int v = sp[t];
        int u = (t >= s) ? sp[t - s] : 0;
        __syncthreads();
        sp[t] = v + u;
        __syncthreads();
    }
    int pre = (t > 0) ? sp[t - 1] : 0;
    #pragma unroll
    for (int i = 0; i < 9; ++i) {
        int idx = base + i;
        if (idx < NBKT) {
            off[idx] = pre;
            cursor[idx] = pre;
            icnt[idx] = 1.0f / fmaxf((float)c[i], 1.0f);
            pre += c[i];
        }
    }
    if (t == 1023) off[NBKT] = sp[1023];
}

__global__ __launch_bounds__(256) void k_fill(const int* __restrict__ ei,
                                              const int* __restrict__ et,
                                              int* __restrict__ cursor,
                                              int* __restrict__ ebuf) {
    int e = blockIdx.x * 256 + threadIdx.x;
    if (e >= NE) return;
    int bkt = et[e] * NN + ei[NE + e];
    int pos = atomicAdd(&cursor[bkt], 1);
    ebuf[pos] = ei[e];  // src
}

// ---------------- temporal: short conv stack + long max ----------------
__global__ __launch_bounds__(64, 1) void k_tshort(
    const float* __restrict__ obs,
    const float* __restrict__ ws1, const float* __restrict__ bs1,
    const float* __restrict__ ws2, const float* __restrict__ bs2,
    float* __restrict__ x)
{
    int idx = blockIdx.x * 64 + threadIdx.x;
    if (idx >= NB * NN) return;
    int b = idx / NN, n = idx - b * NN;

    float row[NC][NT];
    #pragma unroll
    for (int c = 0; c < NC; ++c) {
        const float2* p2 = (const float2*)(obs + ((size_t)(b * NC + c) * NN + n) * NT);
        #pragma unroll
        for (int t = 0; t < NT / 2; ++t) {
            float2 u = p2[t];
            row[c][2 * t] = u.x; row[c][2 * t + 1] = u.y;
        }
    }
    float* xp = x + (size_t)idx * NF;

    float acc2[20];
    #pragma unroll
    for (int o = 0; o < 20; ++o) acc2[o] = bs2[o];
    #pragma unroll
    for (int c = 0; c < 3; ++c) {
        float v[48];
        #pragma unroll
        for (int t = 0; t < 48; ++t) {
            float s = bs1[c];
            #pragma unroll
            for (int i = 0; i < 3; ++i)
                #pragma unroll
                for (int k = 0; k < 3; ++k)
                    s = fmaf(row[i][t + k], ws1[(c * 3 + i) * 3 + k], s);
            v[t] = fmaxf(s, 0.f);
        }
        #pragma unroll
        for (int o = 0; o < 20; ++o) {
            float a = 0.f;
            #pragma unroll
            for (int t = 0; t < 48; ++t)
                a = fmaf(v[t], ws2[(o * 3 + c) * 48 + t], a);
            acc2[o] += a;
        }
    }
    #pragma unroll
    for (int o = 0; o < 20; ++o) xp[o] = fmaxf(acc2[o], 0.f);

    #pragma unroll
    for (int c = 0; c < 3; ++c) {
        float m = row[c][0];
        #pragma unroll
        for (int t = 1; t < NT; ++t) m = fmaxf(m, row[c][t]);
        xp[40 + c] = fmaxf(m, 0.f);
    }
}

// ---------------- temporal: mid conv stack ----------------
__global__ __launch_bounds__(64, 1) void k_tmid(
    const float* __restrict__ obs,
    const float* __restrict__ wm1, const float* __restrict__ bm1,
    const float* __restrict__ wm2, const float* __restrict__ bm2,
    float* __restrict__ x)
{
    int idx = blockIdx.x * 64 + threadIdx.x;
    if (idx >= NB * NN) return;
    int b = idx / NN, n = idx - b * NN;

    float row[NC][NT];
    #pragma unroll
    for (int c = 0; c < NC; ++c) {
        const float2* p2 = (const float2*)(obs + ((size_t)(b * NC + c) * NN + n) * NT);
        #pragma unroll
        for (int t = 0; t < NT / 2; ++t) {
            float2 u = p2[t];
            row[c][2 * t] = u.x; row[c][2 * t + 1] = u.y;
        }
    }
    float* xp = x + (size_t)idx * NF;

    float acc2[20];
    #pragma unroll
    for (int o = 0; o < 20; ++o) acc2[o] = bm2[o];
    #pragma unroll
    for (int c = 0; c < 3; ++c) {
        float v[30];
        #pragma unroll
        for (int t = 0; t < 30; ++t) {
            float s = bm1[c];
            #pragma unroll
            for (int i = 0; i < 3; ++i)
                #pragma unroll
                for (int k = 0; k < 21; ++k)
                    s = fmaf(row[i][t + k], wm1[(c * 3 + i) * 21 + k], s);
            v[t] = fmaxf(s, 0.f);
        }
        #pragma unroll
        for (int o = 0; o < 20; ++o) {
            float a = 0.f;
            #pragma unroll
            for (int t = 0; t < 30; ++t)
                a = fmaf(v[t], wm2[(o * 3 + c) * 30 + t], a);
            acc2[o] += a;
        }
    }
    #pragma unroll
    for (int o = 0; o < 20; ++o) xp[20 + o] = fmaxf(acc2[o], 0.f);
}

// ---------------- RGCN aggregation: z[b,i,r,:] = icnt * sum_src act(in)[b,src,:] ----------------
// wave per (b, dst); lanes = feature; edge loop unrolled x4 for ILP.
// b = blockIdx&15 -> XCD sees 2 batches (~1 MB) -> L2-resident gather.
template<bool LEAKY, bool SEL>
__global__ __launch_bounds__(256) void k_aggregate(
    const float* __restrict__ in, const int* __restrict__ off,
    const int* __restrict__ ebuf, const float* __restrict__ icnt,
    const int* __restrict__ sel, float* __restrict__ z, int ndst)
{
    int blk = blockIdx.x;
    int b = blk & 15, chunk = blk >> 4;
    int wave = threadIdx.x >> 6, lane = threadIdx.x & 63;
    int i = chunk * 4 + wave;
    if (i >= ndst) return;
    int dst = SEL ? sel[i] : i;
    const float* inb = in + (size_t)b * NN * NF;
    float* zp = z + ((size_t)(b * ndst) + i) * (NR * NFP);

    #pragma unroll
    for (int r = 0; r < NR; ++r) {
        int bkt = r * NN + dst;
        int e0 = off[bkt], e1 = off[bkt + 1];
        float zr = 0.f;
        int e = e0;
        for (; e + 4 <= e1; e += 4) {
            int s0 = ebuf[e], s1 = ebuf[e + 1], s2 = ebuf[e + 2], s3 = ebuf[e + 3];
            float v0 = 0.f, v1 = 0.f, v2 = 0.f, v3 = 0.f;
            if (lane < NF) {
                v0 = inb[s0 * NF + lane];
                v1 = inb[s1 * NF + lane];
                v2 = inb[s2 * NF + lane];
                v3 = inb[s3 * NF + lane];
            }
            if (LEAKY) {
                v0 = v0 >= 0.f ? v0 : 0.01f * v0;
                v1 = v1 >= 0.f ? v1 : 0.01f * v1;
                v2 = v2 >= 0.f ? v2 : 0.01f * v2;
                v3 = v3 >= 0.f ? v3 : 0.01f * v3;
            }
            zr += (v0 + v1) + (v2 + v3);
        }
        for (; e < e1; ++e) {
            int s0 = ebuf[e];
            float v0 = 0.f;
            if (lane < NF) v0 = inb[s0 * NF + lane];
            if (LEAKY) v0 = v0 >= 0.f ? v0 : 0.01f * v0;
            zr += v0;
        }
        zr *= icnt[bkt];
        if (lane < NF) zp[r * NFP + lane] = zr;
    }
}

// ---------------- RGCN dense transform ----------------
// thread per output row: out = act(in_row)@root + bias + sum_r z_r@rel_r
// weights/bias via wave-uniform scalar loads; z rows read as float4.
template<bool LEAKY, bool SEL>
__global__ __launch_bounds__(256) void k_xform(
    const float* __restrict__ in, const float* __restrict__ z,
    const float* __restrict__ root, const float* __restrict__ rel,
    const float* __restrict__ bias, const int* __restrict__ sel,
    float* __restrict__ out, int ndst)
{
    int t = blockIdx.x * 256 + threadIdx.x;
    if (t >= NB * ndst) return;
    int b = t / ndst, i = t - b * ndst;
    int node = SEL ? sel[i] : i;

    float acc[NF];
    #pragma unroll
    for (int f = 0; f < NF; ++f) acc[f] = bias[f];

    // self term
    const float* srow = in + ((size_t)b * NN + node) * NF;
    for (int k = 0; k < NF; ++k) {
        float v = srow[k];
        if (LEAKY) v = v >= 0.f ? v : 0.01f * v;
        const float* w = root + k * NF;
        #pragma unroll
        for (int f = 0; f < NF; ++f) acc[f] = fmaf(v, w[f], acc[f]);
    }

    // relation terms
    const float* zp = z + ((size_t)(b * ndst) + i) * (NR * NFP);
    #pragma unroll
    for (int r = 0; r < NR; ++r) {
        const float4* z4 = (const float4*)(zp + r * NFP);
        const float* wr = rel + r * NF * NF;
        for (int k4 = 0; k4 < 10; ++k4) {
            float4 v = z4[k4];
            const float* w = wr + (k4 * 4) * NF;
            #pragma unroll
            for (int f = 0; f < NF; ++f) acc[f] = fmaf(v.x, w[f], acc[f]);
            #pragma unroll
            for (int f = 0; f < NF; ++f) acc[f] = fmaf(v.y, w[NF + f], acc[f]);
            #pragma unroll
            for (int f = 0; f < NF; ++f) acc[f] = fmaf(v.z, w[2 * NF + f], acc[f]);
            #pragma unroll
            for (int f = 0; f < NF; ++f) acc[f] = fmaf(v.w, w[3 * NF + f], acc[f]);
        }
        #pragma unroll
        for (int k = 40; k < NF; ++k) {
            float v = zp[r * NFP + k];
            const float* w = wr + k * NF;
            #pragma unroll
            for (int f = 0; f < NF; ++f) acc[f] = fmaf(v, w[f], acc[f]);
        }
    }

    float* op = out + (size_t)t * NF;
    #pragma unroll
    for (int f = 0; f < NF; ++f) op[f] = acc[f];
}

// ---------------- epilogue: gather + 1x1 conv + softmax ----------------
__device__ inline float wred_max(float v) {
    #pragma unroll
    for (int o = 32; o > 0; o >>= 1) v = fmaxf(v, __shfl_down(v, o));
    return v;
}
__device__ inline float wred_sum(float v) {
    #pragma unroll
    for (int o = 32; o > 0; o >>= 1) v += __shfl_down(v, o);
    return v;
}

__global__ __launch_bounds__(512) void k_final(
    const float* __restrict__ x, const float* __restrict__ h2,
    const float* __restrict__ la, const int* __restrict__ nodes,
    const float* __restrict__ wf, const float* __restrict__ bf,
    float* __restrict__ out)
{
    __shared__ float sl[NS + 1];
    __shared__ float sred[8];
    __shared__ float sbc[2];
    int b = blockIdx.x, tid = threadIdx.x;

    if (tid < NS) {
        int node = nodes[tid];
        float acc = bf[0] + wf[0] * la[b * (NS + 1) + 1 + tid];
        const float* xp = x  + ((size_t)b * NN + node) * NF;
        const float* hp = h2 + ((size_t)b * NS + tid) * NF;   // compact h2
        #pragma unroll
        for (int c = 0; c < NF; ++c) acc = fmaf(wf[1 + c], xp[c], acc);
        #pragma unroll
        for (int c = 0; c < NF; ++c) {
            float t = hp[c];
            t = t >= 0.f ? t : 0.01f * t;   // leaky relu on RGCN2 output
            acc = fmaf(wf[44 + c], t, acc);
        }
        sl[tid + 1] = acc;
    }
    if (tid == 0) sl[0] = 0.f;   // cash logit
    __syncthreads();

    float m = (tid < NS + 1) ? sl[tid] : -3.0e38f;
    m = wred_max(m);
    if ((tid & 63) == 0) sred[tid >> 6] = m;
    __syncthreads();
    if (tid == 0) {
        float mm = sred[0];
        #pragma unroll
        for (int i = 1; i < 8; ++i) mm = fmaxf(mm, sred[i]);
        sbc[0] = mm;
    }
    __syncthreads();
    float mx = sbc[0];
    float e = (tid < NS + 1) ? expf(sl[tid] - mx) : 0.f;
    float s = wred_sum(e);
    if ((tid & 63) == 0) sred[tid >> 6] = s;
    __syncthreads();
    if (tid == 0) {
        float t = 0.f;
        #pragma unroll
        for (int i = 0; i < 8; ++i) t += sred[i];
        sbc[1] = t;
    }
    __syncthreads();
    if (tid < NS + 1) out[(size_t)b * (NS + 1) + tid] = e / sbc[1];
}

extern "C" void kernel_launch(void* const* d_in, const int* in_sizes, int n_in,
                              void* d_out, int out_size, void* d_ws, size_t ws_size,
                              hipStream_t stream)
{
    const float* obs   = (const float*)d_in[0];
    const float* la    = (const float*)d_in[1];
    const int*   ei    = (const int*)d_in[2];
    const int*   et    = (const int*)d_in[3];
    const int*   nodes = (const int*)d_in[4];
    const float* ws1 = (const float*)d_in[5],  *bs1 = (const float*)d_in[6];
    const float* ws2 = (const float*)d_in[7],  *bs2 = (const float*)d_in[8];
    const float* wm1 = (const float*)d_in[9],  *bm1 = (const float*)d_in[10];
    const float* wm2 = (const float*)d_in[11], *bm2 = (const float*)d_in[12];
    const float* root1 = (const float*)d_in[13], *rel1 = (const float*)d_in[14], *bias1 = (const float*)d_in[15];
    const float* root2 = (const float*)d_in[16], *rel2 = (const float*)d_in[17], *bias2 = (const float*)d_in[18];
    const float* wf = (const float*)d_in[19], *bf = (const float*)d_in[20];

    float* wsp  = (float*)d_ws;
    float* x    = wsp + X_OFF;
    float* h1   = wsp + H1_OFF;
    float* h2   = wsp + H2_OFF;
    float* z    = wsp + Z_OFF;
    float* icnt = wsp + ICNT_OFF;
    int*   ibase  = (int*)(wsp + INT_BASE);
    int*   hist   = ibase + HIST_OFF;
    int*   offs   = ibase + OFFS_OFF;
    int*   cursor = ibase + CURS_OFF;
    int*   ebuf   = ibase + EBUF_OFF;

    // CSR build (graph shared by both layers)
    hipMemsetAsync(hist, 0, NBKT * sizeof(int), stream);
    k_hist<<<(NE + 255) / 256, 256, 0, stream>>>(ei, et, hist);
    k_scan<<<1, 1024, 0, stream>>>(hist, offs, cursor, icnt);
    k_fill<<<(NE + 255) / 256, 256, 0, stream>>>(ei, et, cursor, ebuf);

    // temporal features
    k_tshort<<<(NB * NN + 63) / 64, 64, 0, stream>>>(obs, ws1, bs1, ws2, bs2, x);
    k_tmid  <<<(NB * NN + 63) / 64, 64, 0, stream>>>(obs, wm1, bm1, wm2, bm2, x);

    // RGCN layer 1: full graph
    k_aggregate<false, false><<<16 * ((NN + 3) / 4), 256, 0, stream>>>(
        x, offs, ebuf, icnt, nullptr, z, NN);
    k_xform<false, false><<<(NB * NN + 255) / 256, 256, 0, stream>>>(
        x, z, root1, rel1, bias1, nullptr, h1, NN);

    // RGCN layer 2: only the 500 selected dst nodes
    k_aggregate<true, true><<<16 * ((NS + 3) / 4), 256, 0, stream>>>(
        h1, offs, ebuf, icnt, nodes, z, NS);
    k_xform<true, true><<<(NB * NS + 255) / 256, 256, 0, stream>>>(
        h1, z, root2, rel2, bias2, nodes, h2, NS);

    k_final<<<NB, 512, 0, stream>>>(x, h2, la, nodes, wf, bf, (float*)d_out);
}

// Round 4
// 324.423 us; speedup vs baseline: 3.3598x; 1.2756x over previous
//
#include <hip/hip_runtime.h>
#include <math.h>

#define NB 16      // batch
#define NC 3       // obs channels
#define NN 3000    // nodes
#define NT 50      // time
#define NE 96000   // edges
#define NR 3       // relations
#define NS 500     // selected stocks
#define NF 43      // feature dim
#define NFP 44     // padded feature dim (16B-aligned rows)
#define NBKT (NR*NN)   // 9000 CSR buckets keyed (rel, dst)

// ---------------- workspace layout (floats, then ints) ----------------
#define X_OFF    0
#define H1_OFF   (X_OFF  + NB*NN*NFP)
#define H2_OFF   (H1_OFF + NB*NN*NFP)
#define Z_OFF    (H2_OFF + NB*NS*NFP)
#define ICNT_OFF (Z_OFF  + NB*NN*NR*NFP)
#define INT_BASE (ICNT_OFF + NBKT)
#define HIST_OFF  0
#define OFFS_OFF  (HIST_OFF + NBKT)        // NBKT+1 entries
#define CURS_OFF  (OFFS_OFF + NBKT + 1)
#define EBUF_OFF  (CURS_OFF + NBKT)

// ---------------- CSR build ----------------
__global__ __launch_bounds__(256) void k_hist(const int* __restrict__ ei,
                                              const int* __restrict__ et,
                                              int* __restrict__ hist) {
    int e = blockIdx.x * 256 + threadIdx.x;
    if (e >= NE) return;
    atomicAdd(&hist[et[e] * NN + ei[NE + e]], 1);
}

__global__ __launch_bounds__(1024) void k_scan(const int* __restrict__ hist,
                                               int* __restrict__ off,
                                               int* __restrict__ cursor,
                                               float* __restrict__ icnt) {
    __shared__ int sp[1024];
    int t = threadIdx.x;
    int base = t * 9;
    int c[9]; int tot = 0;
    #pragma unroll
    for (int i = 0; i < 9; ++i) {
        int idx = base + i;
        c[i] = (idx < NBKT) ? hist[idx] : 0;
        tot += c[i];
    }
    sp[t] = tot;
    __syncthreads();
    for (int s = 1; s < 1024; s <<= 1) {
        int v = sp[t];
        int u = (t >= s) ? sp[t - s] : 0;
        __syncthreads();
        sp[t] = v + u;
        __syncthreads();
    }
    int pre = (t > 0) ? sp[t - 1] : 0;
    #pragma unroll
    for (int i = 0; i < 9; ++i) {
        int idx = base + i;
        if (idx < NBKT) {
            off[idx] = pre;
            cursor[idx] = pre;
            icnt[idx] = 1.0f / fmaxf((float)c[i], 1.0f);
            pre += c[i];
        }
    }
    if (t == 1023) off[NBKT] = sp[1023];
}

__global__ __launch_bounds__(256) void k_fill(const int* __restrict__ ei,
                                              const int* __restrict__ et,
                                              int* __restrict__ cursor,
                                              int* __restrict__ ebuf) {
    int e = blockIdx.x * 256 + threadIdx.x;
    if (e >= NE) return;
    int bkt = et[e] * NN + ei[NE + e];
    int pos = atomicAdd(&cursor[bkt], 1);
    ebuf[pos] = ei[e];  // src
}

// ---------------- temporal: fused short+long / mid, path = blockIdx&1 ----------------
__global__ __launch_bounds__(64, 1) void k_temporal(
    const float* __restrict__ obs,
    const float* __restrict__ ws1, const float* __restrict__ bs1,
    const float* __restrict__ ws2, const float* __restrict__ bs2,
    const float* __restrict__ wm1, const float* __restrict__ bm1,
    const float* __restrict__ wm2, const float* __restrict__ bm2,
    float* __restrict__ x)
{
    int path = blockIdx.x & 1;
    int idx = (blockIdx.x >> 1) * 64 + threadIdx.x;
    if (idx >= NB * NN) return;
    int b = idx / NN, n = idx - b * NN;

    float row[NC][NT];
    #pragma unroll
    for (int c = 0; c < NC; ++c) {
        const float2* p2 = (const float2*)(obs + ((size_t)(b * NC + c) * NN + n) * NT);
        #pragma unroll
        for (int t = 0; t < NT / 2; ++t) {
            float2 u = p2[t];
            row[c][2 * t] = u.x; row[c][2 * t + 1] = u.y;
        }
    }
    float* xp = x + (size_t)idx * NFP;

    if (path == 0) {
        // short: conv(1x3)->relu->conv(1x48)->relu, plus long max
        float acc2[20];
        #pragma unroll
        for (int o = 0; o < 20; ++o) acc2[o] = bs2[o];
        #pragma unroll
        for (int c = 0; c < 3; ++c) {
            float v[48];
            #pragma unroll
            for (int t = 0; t < 48; ++t) {
                float s = bs1[c];
                #pragma unroll
                for (int i = 0; i < 3; ++i)
                    #pragma unroll
                    for (int k = 0; k < 3; ++k)
                        s = fmaf(row[i][t + k], ws1[(c * 3 + i) * 3 + k], s);
                v[t] = fmaxf(s, 0.f);
            }
            #pragma unroll
            for (int o = 0; o < 20; ++o) {
                float a = 0.f;
                #pragma unroll
                for (int t = 0; t < 48; ++t)
                    a = fmaf(v[t], ws2[(o * 3 + c) * 48 + t], a);
                acc2[o] += a;
            }
        }
        #pragma unroll
        for (int o = 0; o < 20; ++o) xp[o] = fmaxf(acc2[o], 0.f);

        #pragma unroll
        for (int c = 0; c < 3; ++c) {
            float m = row[c][0];
            #pragma unroll
            for (int t = 1; t < NT; ++t) m = fmaxf(m, row[c][t]);
            xp[40 + c] = fmaxf(m, 0.f);
        }
    } else {
        // mid: conv(1x21)->relu->conv(1x30)->relu
        float acc2[20];
        #pragma unroll
        for (int o = 0; o < 20; ++o) acc2[o] = bm2[o];
        #pragma unroll
        for (int c = 0; c < 3; ++c) {
            float v[30];
            #pragma unroll
            for (int t = 0; t < 30; ++t) {
                float s = bm1[c];
                #pragma unroll
                for (int i = 0; i < 3; ++i)
                    #pragma unroll
                    for (int k = 0; k < 21; ++k)
                        s = fmaf(row[i][t + k], wm1[(c * 3 + i) * 21 + k], s);
                v[t] = fmaxf(s, 0.f);
            }
            #pragma unroll
            for (int o = 0; o < 20; ++o) {
                float a = 0.f;
                #pragma unroll
                for (int t = 0; t < 30; ++t)
                    a = fmaf(v[t], wm2[(o * 3 + c) * 30 + t], a);
                acc2[o] += a;
            }
        }
        #pragma unroll
        for (int o = 0; o < 20; ++o) xp[20 + o] = fmaxf(acc2[o], 0.f);
    }
}

// ---------------- RGCN aggregation: z[b,i,r,:] = icnt * sum_src act(in)[b,src,:] ----------------
// wave per (b, dst); lanes = feature; edge loop unrolled x4 for ILP.
// b = blockIdx&15 -> XCD sees 2 batches -> L2-resident gather.
template<bool LEAKY, bool SEL>
__global__ __launch_bounds__(256) void k_aggregate(
    const float* __restrict__ in, const int* __restrict__ off,
    const int* __restrict__ ebuf, const float* __restrict__ icnt,
    const int* __restrict__ sel, float* __restrict__ z, int ndst)
{
    int blk = blockIdx.x;
    int b = blk & 15, chunk = blk >> 4;
    int wave = threadIdx.x >> 6, lane = threadIdx.x & 63;
    int i = chunk * 4 + wave;
    if (i >= ndst) return;
    int dst = SEL ? sel[i] : i;
    const float* inb = in + (size_t)b * NN * NFP;
    float* zp = z + ((size_t)(b * ndst) + i) * (NR * NFP);

    #pragma unroll
    for (int r = 0; r < NR; ++r) {
        int bkt = r * NN + dst;
        int e0 = off[bkt], e1 = off[bkt + 1];
        float zr = 0.f;
        int e = e0;
        for (; e + 4 <= e1; e += 4) {
            int s0 = ebuf[e], s1 = ebuf[e + 1], s2 = ebuf[e + 2], s3 = ebuf[e + 3];
            float v0 = 0.f, v1 = 0.f, v2 = 0.f, v3 = 0.f;
            if (lane < NF) {
                v0 = inb[s0 * NFP + lane];
                v1 = inb[s1 * NFP + lane];
                v2 = inb[s2 * NFP + lane];
                v3 = inb[s3 * NFP + lane];
            }
            if (LEAKY) {
                v0 = v0 >= 0.f ? v0 : 0.01f * v0;
                v1 = v1 >= 0.f ? v1 : 0.01f * v1;
                v2 = v2 >= 0.f ? v2 : 0.01f * v2;
                v3 = v3 >= 0.f ? v3 : 0.01f * v3;
            }
            zr += (v0 + v1) + (v2 + v3);
        }
        for (; e < e1; ++e) {
            int s0 = ebuf[e];
            float v0 = 0.f;
            if (lane < NF) v0 = inb[s0 * NFP + lane];
            if (LEAKY) v0 = v0 >= 0.f ? v0 : 0.01f * v0;
            zr += v0;
        }
        zr *= icnt[bkt];
        if (lane < NF) zp[r * NFP + lane] = zr;
    }
}

// ---------------- RGCN dense transform, k-split across 4 waves ----------------
// Block = 4 waves, 16 rows. Wave w owns weight matrix w (0=root, 1..3=rel_r);
// lane f holds its 43-entry weight column in VGPRs. A-slab is wave-uniform:
// scalar-loaded (readfirstlane forces uniformity) and broadcast into FMAs.
// Partials reduced across waves through LDS. Grid: NB*NDST/16 blocks.
template<bool LEAKY, bool SEL, int NDST>
__global__ __launch_bounds__(256) void k_xform(
    const float* __restrict__ in, const float* __restrict__ z,
    const float* __restrict__ root, const float* __restrict__ rel,
    const float* __restrict__ bias, const int* __restrict__ sel,
    float* __restrict__ out)
{
    __shared__ float sP[8][4][NFP];   // [row-in-chunk][wave][feature]

    int wave = __builtin_amdgcn_readfirstlane(threadIdx.x >> 6);
    int lane = threadIdx.x & 63;
    int rowbase = blockIdx.x * 16;

    // weight column for this (wave, lane), resident in VGPRs
    const float* wbase = (wave == 0) ? root : (rel + (size_t)(wave - 1) * NF * NF);
    float wsl[43];
    #pragma unroll
    for (int j = 0; j < 43; ++j)
        wsl[j] = (lane < NF) ? wbase[j * NF + lane] : 0.f;

    for (int rr8 = 0; rr8 < 16; rr8 += 8) {
        #pragma unroll 1
        for (int rr = 0; rr < 8; ++rr) {
            int t = rowbase + rr8 + rr;
            int b = t / NDST, i = t - b * NDST;
            const float* arow;
            if (wave == 0) {
                int node = SEL ? sel[i] : i;
                arow = in + ((size_t)b * NN + node) * NFP;
            } else {
                arow = z + (size_t)t * (NR * NFP) + (wave - 1) * NFP;
            }
            float a0 = 0.f, a1 = 0.f, a2 = 0.f, a3 = 0.f;
            #pragma unroll
            for (int j = 0; j < 40; j += 4) {
                float v0 = arow[j], v1 = arow[j + 1], v2 = arow[j + 2], v3 = arow[j + 3];
                if (LEAKY && wave == 0) {
                    v0 = v0 >= 0.f ? v0 : 0.01f * v0;
                    v1 = v1 >= 0.f ? v1 : 0.01f * v1;
                    v2 = v2 >= 0.f ? v2 : 0.01f * v2;
                    v3 = v3 >= 0.f ? v3 : 0.01f * v3;
                }
                a0 = fmaf(v0, wsl[j], a0);
                a1 = fmaf(v1, wsl[j + 1], a1);
                a2 = fmaf(v2, wsl[j + 2], a2);
                a3 = fmaf(v3, wsl[j + 3], a3);
            }
            {
                float v0 = arow[40], v1 = arow[41], v2 = arow[42];
                if (LEAKY && wave == 0) {
                    v0 = v0 >= 0.f ? v0 : 0.01f * v0;
                    v1 = v1 >= 0.f ? v1 : 0.01f * v1;
                    v2 = v2 >= 0.f ? v2 : 0.01f * v2;
                }
                a0 = fmaf(v0, wsl[40], a0);
                a1 = fmaf(v1, wsl[41], a1);
                a2 = fmaf(v2, wsl[42], a2);
            }
            if (lane < NF) sP[rr][wave][lane] = (a0 + a1) + (a2 + a3);
        }
        __syncthreads();
        // each wave reduces 2 rows
        if (lane < NF) {
            int r0 = 2 * wave, r1 = 2 * wave + 1;
            float bi = bias[lane];
            float s0 = ((sP[r0][0][lane] + sP[r0][1][lane]) +
                        (sP[r0][2][lane] + sP[r0][3][lane])) + bi;
            float s1 = ((sP[r1][0][lane] + sP[r1][1][lane]) +
                        (sP[r1][2][lane] + sP[r1][3][lane])) + bi;
            out[(size_t)(rowbase + rr8 + r0) * NFP + lane] = s0;
            out[(size_t)(rowbase + rr8 + r1) * NFP + lane] = s1;
        }
        __syncthreads();
    }
}

// ---------------- epilogue: gather + 1x1 conv + softmax ----------------
__device__ inline float wred_max(float v) {
    #pragma unroll
    for (int o = 32; o > 0; o >>= 1) v = fmaxf(v, __shfl_down(v, o));
    return v;
}
__device__ inline float wred_sum(float v) {
    #pragma unroll
    for (int o = 32; o > 0; o >>= 1) v += __shfl_down(v, o);
    return v;
}

__global__ __launch_bounds__(512) void k_final(
    const float* __restrict__ x, const float* __restrict__ h2,
    const float* __restrict__ la, const int* __restrict__ nodes,
    const float* __restrict__ wf, const float* __restrict__ bf,
    float* __restrict__ out)
{
    __shared__ float sl[NS + 1];
    __shared__ float sred[8];
    __shared__ float sbc[2];
    int b = blockIdx.x, tid = threadIdx.x;

    if (tid < NS) {
        int node = nodes[tid];
        float acc = bf[0] + wf[0] * la[b * (NS + 1) + 1 + tid];
        const float* xp = x  + ((size_t)b * NN + node) * NFP;
        const float* hp = h2 + ((size_t)b * NS + tid) * NFP;   // compact h2
        #pragma unroll
        for (int c = 0; c < NF; ++c) acc = fmaf(wf[1 + c], xp[c], acc);
        #pragma unroll
        for (int c = 0; c < NF; ++c) {
            float t = hp[c];
            t = t >= 0.f ? t : 0.01f * t;   // leaky relu on RGCN2 output
            acc = fmaf(wf[44 + c], t, acc);
        }
        sl[tid + 1] = acc;
    }
    if (tid == 0) sl[0] = 0.f;   // cash logit
    __syncthreads();

    float m = (tid < NS + 1) ? sl[tid] : -3.0e38f;
    m = wred_max(m);
    if ((tid & 63) == 0) sred[tid >> 6] = m;
    __syncthreads();
    if (tid == 0) {
        float mm = sred[0];
        #pragma unroll
        for (int i = 1; i < 8; ++i) mm = fmaxf(mm, sred[i]);
        sbc[0] = mm;
    }
    __syncthreads();
    float mx = sbc[0];
    float e = (tid < NS + 1) ? expf(sl[tid] - mx) : 0.f;
    float s = wred_sum(e);
    if ((tid & 63) == 0) sred[tid >> 6] = s;
    __syncthreads();
    if (tid == 0) {
        float t = 0.f;
        #pragma unroll
        for (int i = 0; i < 8; ++i) t += sred[i];
        sbc[1] = t;
    }
    __syncthreads();
    if (tid < NS + 1) out[(size_t)b * (NS + 1) + tid] = e / sbc[1];
}

extern "C" void kernel_launch(void* const* d_in, const int* in_sizes, int n_in,
                              void* d_out, int out_size, void* d_ws, size_t ws_size,
                              hipStream_t stream)
{
    const float* obs   = (const float*)d_in[0];
    const float* la    = (const float*)d_in[1];
    const int*   ei    = (const int*)d_in[2];
    const int*   et    = (const int*)d_in[3];
    const int*   nodes = (const int*)d_in[4];
    const float* ws1 = (const float*)d_in[5],  *bs1 = (const float*)d_in[6];
    const float* ws2 = (const float*)d_in[7],  *bs2 = (const float*)d_in[8];
    const float* wm1 = (const float*)d_in[9],  *bm1 = (const float*)d_in[10];
    const float* wm2 = (const float*)d_in[11], *bm2 = (const float*)d_in[12];
    const float* root1 = (const float*)d_in[13], *rel1 = (const float*)d_in[14], *bias1 = (const float*)d_in[15];
    const float* root2 = (const float*)d_in[16], *rel2 = (const float*)d_in[17], *bias2 = (const float*)d_in[18];
    const float* wf = (const float*)d_in[19], *bf = (const float*)d_in[20];

    float* wsp  = (float*)d_ws;
    float* x    = wsp + X_OFF;
    float* h1   = wsp + H1_OFF;
    float* h2   = wsp + H2_OFF;
    float* z    = wsp + Z_OFF;
    float* icnt = wsp + ICNT_OFF;
    int*   ibase  = (int*)(wsp + INT_BASE);
    int*   hist   = ibase + HIST_OFF;
    int*   offs   = ibase + OFFS_OFF;
    int*   cursor = ibase + CURS_OFF;
    int*   ebuf   = ibase + EBUF_OFF;

    // CSR build (graph shared by both layers)
    hipMemsetAsync(hist, 0, NBKT * sizeof(int), stream);
    k_hist<<<(NE + 255) / 256, 256, 0, stream>>>(ei, et, hist);
    k_scan<<<1, 1024, 0, stream>>>(hist, offs, cursor, icnt);
    k_fill<<<(NE + 255) / 256, 256, 0, stream>>>(ei, et, cursor, ebuf);

    // temporal features (path = blockIdx&1: even=short+long, odd=mid)
    k_temporal<<<2 * ((NB * NN + 63) / 64), 64, 0, stream>>>(
        obs, ws1, bs1, ws2, bs2, wm1, bm1, wm2, bm2, x);

    // RGCN layer 1: full graph
    k_aggregate<false, false><<<16 * ((NN + 3) / 4), 256, 0, stream>>>(
        x, offs, ebuf, icnt, nullptr, z, NN);
    k_xform<false, false, NN><<<NB * NN / 16, 256, 0, stream>>>(
        x, z, root1, rel1, bias1, nullptr, h1);

    // RGCN layer 2: only the 500 selected dst nodes
    k_aggregate<true, true><<<16 * ((NS + 3) / 4), 256, 0, stream>>>(
        h1, offs, ebuf, icnt, nodes, z, NS);
    k_xform<true, true, NS><<<NB * NS / 16, 256, 0, stream>>>(
        h1, z, root2, rel2, bias2, nodes, h2);

    k_final<<<NB, 512, 0, stream>>>(x, h2, la, nodes, wf, bf, (float*)d_out);
}

// Round 5
// 299.638 us; speedup vs baseline: 3.6377x; 1.0827x over previous
//
#include <hip/hip_runtime.h>
#include <math.h>

#define NB 16      // batch
#define NC 3       // obs channels
#define NN 3000    // nodes
#define NT 50      // time
#define NE 96000   // edges
#define NR 3       // relations
#define NS 500     // selected stocks
#define NF 43      // feature dim
#define NFP 44     // padded feature dim (16B-aligned rows)
#define NBKT (NR*NN)   // 9000 buckets keyed (rel, dst)
#define CAP 96     // fixed bucket capacity (mean 10.7, Poisson tail @96 ~ 0)

// ---------------- workspace layout (floats, then ints) ----------------
#define X_OFF    0
#define H1_OFF   (X_OFF  + NB*NN*NFP)
#define H2_OFF   (H1_OFF + NB*NN*NFP)
#define Z_OFF    (H2_OFF + NB*NS*NFP)
#define ICNT_OFF (Z_OFF  + NB*NN*NR*NFP)
#define INT_BASE (ICNT_OFF + NBKT)
#define CNT_OFF  0
#define EBUF_OFF (CNT_OFF + NBKT)

// ---------------- bucket fill (count + place, no scan) ----------------
__global__ __launch_bounds__(256) void k_fill(const int* __restrict__ ei,
                                              const int* __restrict__ et,
                                              int* __restrict__ cnt,
                                              int* __restrict__ ebuf) {
    int e = blockIdx.x * 256 + threadIdx.x;
    if (e >= NE) return;
    int bkt = et[e] * NN + ei[NE + e];
    int pos = atomicAdd(&cnt[bkt], 1);
    if (pos < CAP) ebuf[bkt * CAP + pos] = ei[e];  // src
}

__global__ __launch_bounds__(256) void k_icnt(const int* __restrict__ cnt,
                                              float* __restrict__ icnt) {
    int i = blockIdx.x * 256 + threadIdx.x;
    if (i >= NBKT) return;
    icnt[i] = 1.0f / fmaxf((float)cnt[i], 1.0f);
}

// ---------------- temporal features: 64 nodes x 4 t-slice waves ----------------
// wave s: short outputs t in [12s, 12s+12), window wS[3][14] from base 12s;
//         mid outputs t in [8s, 8s+8) (s<3) / [24,30) (s=3), window wM[3][28]
//         from base 8s / 24 (local mid index always starts at 0).
// Partials reduced across waves via LDS; bias+relu in the reducer.
// Long max over mid windows (union covers [0,50); zero-pad safe under relu).
__global__ __launch_bounds__(256, 3) void k_temporal(
    const float* __restrict__ obs,
    const float* __restrict__ ws1, const float* __restrict__ bs1,
    const float* __restrict__ ws2, const float* __restrict__ bs2,
    const float* __restrict__ wm1, const float* __restrict__ bm1,
    const float* __restrict__ wm2, const float* __restrict__ bm2,
    float* __restrict__ x)
{
    __shared__ float sp[4][64][25];   // [wave][node][partial]; stride 25: conflict-free
    int tid  = threadIdx.x;
    int wave = __builtin_amdgcn_readfirstlane(tid >> 6);
    int lane = tid & 63;
    int idx  = blockIdx.x * 64 + lane;       // (b,n), exact: 750*64 = 48000
    int b = idx / NN, n = idx - b * NN;

    // ---- phase A: short conv stack, slice of 12 t's ----
    {
        float wS[3][14];
        int base = 12 * wave;
        #pragma unroll
        for (int c = 0; c < 3; ++c) {
            const float2* p2 = (const float2*)(obs + ((size_t)(b * NC + c) * NN + n) * NT + base);
            #pragma unroll
            for (int jj = 0; jj < 7; ++jj) {
                float2 u = p2[jj];
                wS[c][2 * jj] = u.x; wS[c][2 * jj + 1] = u.y;
            }
        }
        float acc[20];
        #pragma unroll
        for (int o = 0; o < 20; ++o) acc[o] = 0.f;
        #pragma unroll
        for (int j = 0; j < 12; ++j) {
            float y[3];
            #pragma unroll
            for (int c = 0; c < 3; ++c) {
                float s = bs1[c];
                #pragma unroll
                for (int i = 0; i < 3; ++i)
                    #pragma unroll
                    for (int k = 0; k < 3; ++k)
                        s = fmaf(wS[i][j + k], ws1[(c * 3 + i) * 3 + k], s);
                y[c] = fmaxf(s, 0.f);
            }
            int gt = base + j;   // wave-uniform -> scalar loads of ws2
            #pragma unroll
            for (int o = 0; o < 20; ++o) {
                float a = acc[o];
                #pragma unroll
                for (int c = 0; c < 3; ++c)
                    a = fmaf(y[c], ws2[(o * 3 + c) * 48 + gt], a);
                acc[o] = a;
            }
        }
        #pragma unroll
        for (int o = 0; o < 20; ++o) sp[wave][lane][o] = acc[o];
    }
    __syncthreads();
    // reduce short: 64 nodes x 20 outputs = 1280 = 5*256
    #pragma unroll
    for (int q = 0; q < 5; ++q) {
        int item = q * 256 + tid;
        int node = item / 20, o = item - node * 20;
        float s = ((sp[0][node][o] + sp[1][node][o]) +
                   (sp[2][node][o] + sp[3][node][o])) + bs2[o];
        x[(size_t)(blockIdx.x * 64 + node) * NFP + o] = fmaxf(s, 0.f);
    }
    __syncthreads();

    // ---- phase B: mid conv stack + long max ----
    {
        float wM[3][28];
        int mbase = (wave < 3) ? 8 * wave : 24;
        int nld   = (wave < 3) ? 14 : 13;    // floats2 to load (window 28 / 26)
        #pragma unroll
        for (int c = 0; c < 3; ++c) {
            const float2* p2 = (const float2*)(obs + ((size_t)(b * NC + c) * NN + n) * NT + mbase);
            #pragma unroll
            for (int jj = 0; jj < 14; ++jj) {
                if (jj < nld) {
                    float2 u = p2[jj];
                    wM[c][2 * jj] = u.x; wM[c][2 * jj + 1] = u.y;
                } else {
                    wM[c][2 * jj] = 0.f; wM[c][2 * jj + 1] = 0.f;
                }
            }
        }
        float cmax[3];
        #pragma unroll
        for (int c = 0; c < 3; ++c) {
            float m = wM[c][0];
            #pragma unroll
            for (int t = 1; t < 28; ++t) m = fmaxf(m, wM[c][t]);
            cmax[c] = m;   // zero-pad safe: relu follows
        }
        float acc[20];
        #pragma unroll
        for (int o = 0; o < 20; ++o) acc[o] = 0.f;
        int cntM = (wave < 3) ? 8 : 6;
        #pragma unroll
        for (int j = 0; j < 8; ++j) {
            if (j < cntM) {
                float y[3];
                #pragma unroll
                for (int c = 0; c < 3; ++c) {
                    float s = bm1[c];
                    #pragma unroll
                    for (int i = 0; i < 3; ++i)
                        #pragma unroll
                        for (int k = 0; k < 21; ++k)
                            s = fmaf(wM[i][j + k], wm1[(c * 3 + i) * 21 + k], s);
                    y[c] = fmaxf(s, 0.f);
                }
                int gt = mbase + j;   // wave-uniform -> scalar loads of wm2
                #pragma unroll
                for (int o = 0; o < 20; ++o) {
                    float a = acc[o];
                    #pragma unroll
                    for (int c = 0; c < 3; ++c)
                        a = fmaf(y[c], wm2[(o * 3 + c) * 30 + gt], a);
                    acc[o] = a;
                }
            }
        }
        #pragma unroll
        for (int o = 0; o < 20; ++o) sp[wave][lane][o] = acc[o];
        #pragma unroll
        for (int c = 0; c < 3; ++c) sp[wave][lane][20 + c] = cmax[c];
    }
    __syncthreads();
    // reduce mid + long: 64 nodes x 23 = 1472 items
    #pragma unroll
    for (int q = 0; q < 6; ++q) {
        int item = q * 256 + tid;
        if (item < 1472) {
            int node = item / 23, o = item - node * 23;
            size_t row = (size_t)(blockIdx.x * 64 + node) * NFP;
            if (o < 20) {
                float s = ((sp[0][node][o] + sp[1][node][o]) +
                           (sp[2][node][o] + sp[3][node][o])) + bm2[o];
                x[row + 20 + o] = fmaxf(s, 0.f);
            } else {
                float m = fmaxf(fmaxf(sp[0][node][o], sp[1][node][o]),
                                fmaxf(sp[2][node][o], sp[3][node][o]));
                x[row + 40 + (o - 20)] = fmaxf(m, 0.f);
            }
        }
    }
}

// ---------------- RGCN aggregation: z[b,i,r,:] = icnt * sum_src act(in)[b,src,:] ----------------
// wave per (b, dst); lanes = feature; edge loop unrolled x4 for ILP.
// b = blockIdx&15 -> XCD sees 2 batches -> L2-resident gather.
template<bool LEAKY, bool SEL>
__global__ __launch_bounds__(256) void k_aggregate(
    const float* __restrict__ in, const int* __restrict__ cnt,
    const int* __restrict__ ebuf, const float* __restrict__ icnt,
    const int* __restrict__ sel, float* __restrict__ z, int ndst)
{
    int blk = blockIdx.x;
    int b = blk & 15, chunk = blk >> 4;
    int wave = threadIdx.x >> 6, lane = threadIdx.x & 63;
    int i = chunk * 4 + wave;
    if (i >= ndst) return;
    int dst = SEL ? sel[i] : i;
    const float* inb = in + (size_t)b * NN * NFP;
    float* zp = z + ((size_t)(b * ndst) + i) * (NR * NFP);

    #pragma unroll
    for (int r = 0; r < NR; ++r) {
        int bkt = r * NN + dst;
        int cv = cnt[bkt]; if (cv > CAP) cv = CAP;
        int e0 = bkt * CAP, e1 = e0 + cv;
        float zr = 0.f;
        int e = e0;
        for (; e + 4 <= e1; e += 4) {
            int s0 = ebuf[e], s1 = ebuf[e + 1], s2 = ebuf[e + 2], s3 = ebuf[e + 3];
            float v0 = 0.f, v1 = 0.f, v2 = 0.f, v3 = 0.f;
            if (lane < NF) {
                v0 = inb[s0 * NFP + lane];
                v1 = inb[s1 * NFP + lane];
                v2 = inb[s2 * NFP + lane];
                v3 = inb[s3 * NFP + lane];
            }
            if (LEAKY) {
                v0 = v0 >= 0.f ? v0 : 0.01f * v0;
                v1 = v1 >= 0.f ? v1 : 0.01f * v1;
                v2 = v2 >= 0.f ? v2 : 0.01f * v2;
                v3 = v3 >= 0.f ? v3 : 0.01f * v3;
            }
            zr += (v0 + v1) + (v2 + v3);
        }
        for (; e < e1; ++e) {
            int s0 = ebuf[e];
            float v0 = 0.f;
            if (lane < NF) v0 = inb[s0 * NFP + lane];
            if (LEAKY) v0 = v0 >= 0.f ? v0 : 0.01f * v0;
            zr += v0;
        }
        zr *= icnt[bkt];
        if (lane < NF) zp[r * NFP + lane] = zr;
    }
}

// ---------------- RGCN dense transform, k-split across 4 waves ----------------
template<bool LEAKY, bool SEL, int NDST>
__global__ __launch_bounds__(256) void k_xform(
    const float* __restrict__ in, const float* __restrict__ z,
    const float* __restrict__ root, const float* __restrict__ rel,
    const float* __restrict__ bias, const int* __restrict__ sel,
    float* __restrict__ out)
{
    __shared__ float sP[8][4][NFP];   // [row-in-chunk][wave][feature]

    int wave = __builtin_amdgcn_readfirstlane(threadIdx.x >> 6);
    int lane = threadIdx.x & 63;
    int rowbase = blockIdx.x * 16;

    const float* wbase = (wave == 0) ? root : (rel + (size_t)(wave - 1) * NF * NF);
    float wsl[43];
    #pragma unroll
    for (int j = 0; j < 43; ++j)
        wsl[j] = (lane < NF) ? wbase[j * NF + lane] : 0.f;

    for (int rr8 = 0; rr8 < 16; rr8 += 8) {
        #pragma unroll 1
        for (int rr = 0; rr < 8; ++rr) {
            int t = rowbase + rr8 + rr;
            int b = t / NDST, i = t - b * NDST;
            const float* arow;
            if (wave == 0) {
                int node = SEL ? sel[i] : i;
                arow = in + ((size_t)b * NN + node) * NFP;
            } else {
                arow = z + (size_t)t * (NR * NFP) + (wave - 1) * NFP;
            }
            float a0 = 0.f, a1 = 0.f, a2 = 0.f, a3 = 0.f;
            #pragma unroll
            for (int j = 0; j < 40; j += 4) {
                float v0 = arow[j], v1 = arow[j + 1], v2 = arow[j + 2], v3 = arow[j + 3];
                if (LEAKY && wave == 0) {
                    v0 = v0 >= 0.f ? v0 : 0.01f * v0;
                    v1 = v1 >= 0.f ? v1 : 0.01f * v1;
                    v2 = v2 >= 0.f ? v2 : 0.01f * v2;
                    v3 = v3 >= 0.f ? v3 : 0.01f * v3;
                }
                a0 = fmaf(v0, wsl[j], a0);
                a1 = fmaf(v1, wsl[j + 1], a1);
                a2 = fmaf(v2, wsl[j + 2], a2);
                a3 = fmaf(v3, wsl[j + 3], a3);
            }
            {
                float v0 = arow[40], v1 = arow[41], v2 = arow[42];
                if (LEAKY && wave == 0) {
                    v0 = v0 >= 0.f ? v0 : 0.01f * v0;
                    v1 = v1 >= 0.f ? v1 : 0.01f * v1;
                    v2 = v2 >= 0.f ? v2 : 0.01f * v2;
                }
                a0 = fmaf(v0, wsl[40], a0);
                a1 = fmaf(v1, wsl[41], a1);
                a2 = fmaf(v2, wsl[42], a2);
            }
            if (lane < NF) sP[rr][wave][lane] = (a0 + a1) + (a2 + a3);
        }
        __syncthreads();
        if (lane < NF) {
            int r0 = 2 * wave, r1 = 2 * wave + 1;
            float bi = bias[lane];
            float s0 = ((sP[r0][0][lane] + sP[r0][1][lane]) +
                        (sP[r0][2][lane] + sP[r0][3][lane])) + bi;
            float s1 = ((sP[r1][0][lane] + sP[r1][1][lane]) +
                        (sP[r1][2][lane] + sP[r1][3][lane])) + bi;
            out[(size_t)(rowbase + rr8 + r0) * NFP + lane] = s0;
            out[(size_t)(rowbase + rr8 + r1) * NFP + lane] = s1;
        }
        __syncthreads();
    }
}

// ---------------- epilogue: gather + 1x1 conv + softmax ----------------
__device__ inline float wred_max(float v) {
    #pragma unroll
    for (int o = 32; o > 0; o >>= 1) v = fmaxf(v, __shfl_down(v, o));
    return v;
}
__device__ inline float wred_sum(float v) {
    #pragma unroll
    for (int o = 32; o > 0; o >>= 1) v += __shfl_down(v, o);
    return v;
}

__global__ __launch_bounds__(512) void k_final(
    const float* __restrict__ x, const float* __restrict__ h2,
    const float* __restrict__ la, const int* __restrict__ nodes,
    const float* __restrict__ wf, const float* __restrict__ bf,
    float* __restrict__ out)
{
    __shared__ float sl[NS + 1];
    __shared__ float sred[8];
    __shared__ float sbc[2];
    int b = blockIdx.x, tid = threadIdx.x;

    if (tid < NS) {
        int node = nodes[tid];
        float acc = bf[0] + wf[0] * la[b * (NS + 1) + 1 + tid];
        const float* xp = x  + ((size_t)b * NN + node) * NFP;
        const float* hp = h2 + ((size_t)b * NS + tid) * NFP;   // compact h2
        #pragma unroll
        for (int c = 0; c < NF; ++c) acc = fmaf(wf[1 + c], xp[c], acc);
        #pragma unroll
        for (int c = 0; c < NF; ++c) {
            float t = hp[c];
            t = t >= 0.f ? t : 0.01f * t;   // leaky relu on RGCN2 output
            acc = fmaf(wf[44 + c], t, acc);
        }
        sl[tid + 1] = acc;
    }
    if (tid == 0) sl[0] = 0.f;   // cash logit
    __syncthreads();

    float m = (tid < NS + 1) ? sl[tid] : -3.0e38f;
    m = wred_max(m);
    if ((tid & 63) == 0) sred[tid >> 6] = m;
    __syncthreads();
    if (tid == 0) {
        float mm = sred[0];
        #pragma unroll
        for (int i = 1; i < 8; ++i) mm = fmaxf(mm, sred[i]);
        sbc[0] = mm;
    }
    __syncthreads();
    float mx = sbc[0];
    float e = (tid < NS + 1) ? expf(sl[tid] - mx) : 0.f;
    float s = wred_sum(e);
    if ((tid & 63) == 0) sred[tid >> 6] = s;
    __syncthreads();
    if (tid == 0) {
        float t = 0.f;
        #pragma unroll
        for (int i = 0; i < 8; ++i) t += sred[i];
        sbc[1] = t;
    }
    __syncthreads();
    if (tid < NS + 1) out[(size_t)b * (NS + 1) + tid] = e / sbc[1];
}

extern "C" void kernel_launch(void* const* d_in, const int* in_sizes, int n_in,
                              void* d_out, int out_size, void* d_ws, size_t ws_size,
                              hipStream_t stream)
{
    const float* obs   = (const float*)d_in[0];
    const float* la    = (const float*)d_in[1];
    const int*   ei    = (const int*)d_in[2];
    const int*   et    = (const int*)d_in[3];
    const int*   nodes = (const int*)d_in[4];
    const float* ws1 = (const float*)d_in[5],  *bs1 = (const float*)d_in[6];
    const float* ws2 = (const float*)d_in[7],  *bs2 = (const float*)d_in[8];
    const float* wm1 = (const float*)d_in[9],  *bm1 = (const float*)d_in[10];
    const float* wm2 = (const float*)d_in[11], *bm2 = (const float*)d_in[12];
    const float* root1 = (const float*)d_in[13], *rel1 = (const float*)d_in[14], *bias1 = (const float*)d_in[15];
    const float* root2 = (const float*)d_in[16], *rel2 = (const float*)d_in[17], *bias2 = (const float*)d_in[18];
    const float* wf = (const float*)d_in[19], *bf = (const float*)d_in[20];

    float* wsp  = (float*)d_ws;
    float* x    = wsp + X_OFF;
    float* h1   = wsp + H1_OFF;
    float* h2   = wsp + H2_OFF;
    float* z    = wsp + Z_OFF;
    float* icnt = wsp + ICNT_OFF;
    int*   ibase = (int*)(wsp + INT_BASE);
    int*   cnt   = ibase + CNT_OFF;
    int*   ebuf  = ibase + EBUF_OFF;

    // bucket build (graph shared by both layers): count+place, no scan
    hipMemsetAsync(cnt, 0, NBKT * sizeof(int), stream);
    k_fill<<<(NE + 255) / 256, 256, 0, stream>>>(ei, et, cnt, ebuf);
    k_icnt<<<(NBKT + 255) / 256, 256, 0, stream>>>(cnt, icnt);

    // temporal features: 750 blocks x (64 nodes, 4 t-slice waves)
    k_temporal<<<NB * NN / 64, 256, 0, stream>>>(
        obs, ws1, bs1, ws2, bs2, wm1, bm1, wm2, bm2, x);

    // RGCN layer 1: full graph
    k_aggregate<false, false><<<16 * ((NN + 3) / 4), 256, 0, stream>>>(
        x, cnt, ebuf, icnt, nullptr, z, NN);
    k_xform<false, false, NN><<<NB * NN / 16, 256, 0, stream>>>(
        x, z, root1, rel1, bias1, nullptr, h1);

    // RGCN layer 2: only the 500 selected dst nodes
    k_aggregate<true, true><<<16 * ((NS + 3) / 4), 256, 0, stream>>>(
        h1, cnt, ebuf, icnt, nodes, z, NS);
    k_xform<true, true, NS><<<NB * NS / 16, 256, 0, stream>>>(
        h1, z, root2, rel2, bias2, nodes, h2);

    k_final<<<NB, 512, 0, stream>>>(x, h2, la, nodes, wf, bf, (float*)d_out);
}

// Round 6
// 265.974 us; speedup vs baseline: 4.0981x; 1.1266x over previous
//
#include <hip/hip_runtime.h>
#include <math.h>

#define NB 16      // batch
#define NC 3       // obs channels
#define NN 3000    // nodes
#define NT 50      // time
#define NE 96000   // edges
#define NR 3       // relations
#define NS 500     // selected stocks
#define NF 43      // feature dim
#define NFP 44     // padded feature dim
#define NBF (NB*NFP)   // 704 = 11 * 64: transposed row length per node
#define NBKT (NR*NN)   // 9000 buckets keyed (rel, dst)
#define CAP 96     // fixed bucket capacity (mean 10.7; Poisson tail @96 ~ 0)

// ---------------- workspace layout (floats, then ints) ----------------
// x_t / h1_t: [node][b*44+f]  (704 floats per node)
// z:          [bucket-row][b*44+f]  (L1: 9000 rows; L2 reuses first 1500)
// h2:         [b][NS][NFP] compact
#define XT_OFF   0
#define H1_OFF   (XT_OFF + NN*NBF)
#define Z_OFF    (H1_OFF + NN*NBF)
#define H2_OFF   (Z_OFF  + NBKT*NBF)
#define INT_BASE (H2_OFF + NB*NS*NFP)
#define CNT_OFF  0
#define EBUF_OFF (CNT_OFF + NBKT)   // byte-offset stays 16B-aligned (checked)

// ---------------- fused front: temporal features + bucket fill ----------------
// blocks [0,750):   temporal (64 nodes x 4 t-slice waves)
// blocks [750,1125): bucket fill (count + place, no scan)
__global__ __launch_bounds__(256, 3) void k_front(
    const float* __restrict__ obs,
    const float* __restrict__ ws1, const float* __restrict__ bs1,
    const float* __restrict__ ws2, const float* __restrict__ bs2,
    const float* __restrict__ wm1, const float* __restrict__ bm1,
    const float* __restrict__ wm2, const float* __restrict__ bm2,
    float* __restrict__ x,
    const int* __restrict__ ei, const int* __restrict__ et,
    int* __restrict__ cnt, int* __restrict__ ebuf)
{
    __shared__ float sp[4][64][25];   // [wave][node][partial]; stride 25: conflict-free
    int tid = threadIdx.x;

    if (blockIdx.x >= 750) {
        // ---- bucket fill ----
        int e = (blockIdx.x - 750) * 256 + tid;
        if (e < NE) {
            int bkt = et[e] * NN + ei[NE + e];
            int pos = atomicAdd(&cnt[bkt], 1);
            if (pos < CAP) ebuf[bkt * CAP + pos] = ei[e];  // src
        }
        return;
    }

    int wave = __builtin_amdgcn_readfirstlane(tid >> 6);
    int lane = tid & 63;
    int idx  = blockIdx.x * 64 + lane;       // (b,n): 750*64 = 48000 exact
    int b = idx / NN, n = idx - b * NN;

    // ---- phase A: short conv stack, slice of 12 t's ----
    {
        float wS[3][14];
        int base = 12 * wave;
        #pragma unroll
        for (int c = 0; c < 3; ++c) {
            const float2* p2 = (const float2*)(obs + ((size_t)(b * NC + c) * NN + n) * NT + base);
            #pragma unroll
            for (int jj = 0; jj < 7; ++jj) {
                float2 u = p2[jj];
                wS[c][2 * jj] = u.x; wS[c][2 * jj + 1] = u.y;
            }
        }
        float acc[20];
        #pragma unroll
        for (int o = 0; o < 20; ++o) acc[o] = 0.f;
        #pragma unroll
        for (int j = 0; j < 12; ++j) {
            float y[3];
            #pragma unroll
            for (int c = 0; c < 3; ++c) {
                float s = bs1[c];
                #pragma unroll
                for (int i = 0; i < 3; ++i)
                    #pragma unroll
                    for (int k = 0; k < 3; ++k)
                        s = fmaf(wS[i][j + k], ws1[(c * 3 + i) * 3 + k], s);
                y[c] = fmaxf(s, 0.f);
            }
            int gt = base + j;   // wave-uniform -> scalar loads of ws2
            #pragma unroll
            for (int o = 0; o < 20; ++o) {
                float a = acc[o];
                #pragma unroll
                for (int c = 0; c < 3; ++c)
                    a = fmaf(y[c], ws2[(o * 3 + c) * 48 + gt], a);
                acc[o] = a;
            }
        }
        #pragma unroll
        for (int o = 0; o < 20; ++o) sp[wave][lane][o] = acc[o];
    }
    __syncthreads();
    // reduce short: 64 nodes x 20 outputs = 1280 = 5*256
    #pragma unroll
    for (int q = 0; q < 5; ++q) {
        int item = q * 256 + tid;
        int node = item / 20, o = item - node * 20;
        int g = blockIdx.x * 64 + node;
        int bb = g / NN, nn = g - bb * NN;
        float s = ((sp[0][node][o] + sp[1][node][o]) +
                   (sp[2][node][o] + sp[3][node][o])) + bs2[o];
        x[(size_t)nn * NBF + bb * NFP + o] = fmaxf(s, 0.f);
    }
    __syncthreads();

    // ---- phase B: mid conv stack + long max ----
    {
        float wM[3][28];
        int mbase = (wave < 3) ? 8 * wave : 24;
        int nld   = (wave < 3) ? 14 : 13;
        #pragma unroll
        for (int c = 0; c < 3; ++c) {
            const float2* p2 = (const float2*)(obs + ((size_t)(b * NC + c) * NN + n) * NT + mbase);
            #pragma unroll
            for (int jj = 0; jj < 14; ++jj) {
                if (jj < nld) {
                    float2 u = p2[jj];
                    wM[c][2 * jj] = u.x; wM[c][2 * jj + 1] = u.y;
                } else {
                    wM[c][2 * jj] = 0.f; wM[c][2 * jj + 1] = 0.f;
                }
            }
        }
        float cmax[3];
        #pragma unroll
        for (int c = 0; c < 3; ++c) {
            float m = wM[c][0];
            #pragma unroll
            for (int t = 1; t < 28; ++t) m = fmaxf(m, wM[c][t]);
            cmax[c] = m;   // zero-pad safe: relu follows
        }
        float acc[20];
        #pragma unroll
        for (int o = 0; o < 20; ++o) acc[o] = 0.f;
        int cntM = (wave < 3) ? 8 : 6;
        #pragma unroll
        for (int j = 0; j < 8; ++j) {
            if (j < cntM) {
                float y[3];
                #pragma unroll
                for (int c = 0; c < 3; ++c) {
                    float s = bm1[c];
                    #pragma unroll
                    for (int i = 0; i < 3; ++i)
                        #pragma unroll
                        for (int k = 0; k < 21; ++k)
                            s = fmaf(wM[i][j + k], wm1[(c * 3 + i) * 21 + k], s);
                    y[c] = fmaxf(s, 0.f);
                }
                int gt = mbase + j;
                #pragma unroll
                for (int o = 0; o < 20; ++o) {
                    float a = acc[o];
                    #pragma unroll
                    for (int c = 0; c < 3; ++c)
                        a = fmaf(y[c], wm2[(o * 3 + c) * 30 + gt], a);
                    acc[o] = a;
                }
            }
        }
        #pragma unroll
        for (int o = 0; o < 20; ++o) sp[wave][lane][o] = acc[o];
        #pragma unroll
        for (int c = 0; c < 3; ++c) sp[wave][lane][20 + c] = cmax[c];
    }
    __syncthreads();
    // reduce mid + long: 64 nodes x 23 = 1472 items
    #pragma unroll
    for (int q = 0; q < 6; ++q) {
        int item = q * 256 + tid;
        if (item < 1472) {
            int node = item / 23, o = item - node * 23;
            int g = blockIdx.x * 64 + node;
            int bb = g / NN, nn = g - bb * NN;
            size_t row = (size_t)nn * NBF + bb * NFP;
            if (o < 20) {
                float s = ((sp[0][node][o] + sp[1][node][o]) +
                           (sp[2][node][o] + sp[3][node][o])) + bm2[o];
                x[row + 20 + o] = fmaxf(s, 0.f);
            } else {
                float m = fmaxf(fmaxf(sp[0][node][o], sp[1][node][o]),
                                fmaxf(sp[2][node][o], sp[3][node][o]));
                x[row + 40 + (o - 20)] = fmaxf(m, 0.f);
            }
        }
    }
}

// ---------------- RGCN aggregation (transposed): wave per bucket, all batches ----------------
// z[zrow][j*64+lane] = (1/max(cnt,1)) * sum_{src in bucket} act(in_t)[src][j*64+lane]
// 11 coalesced 256-B loads per edge (immediate offsets), int4 index prefetch.
template<bool LEAKY, bool SEL>
__global__ __launch_bounds__(256) void k_aggregate(
    const float* __restrict__ in, const int* __restrict__ cnt,
    const int* __restrict__ ebuf, const int* __restrict__ sel,
    float* __restrict__ z, int nbi)
{
    int wave = threadIdx.x >> 6, lane = threadIdx.x & 63;
    int bi = blockIdx.x * 4 + wave;
    if (bi >= nbi) return;

    int bkt;
    if (SEL) {
        int r = bi / NS, ii = bi - r * NS;
        int dst = __builtin_amdgcn_readfirstlane(sel[ii]);
        bkt = r * NN + dst;
    } else {
        bkt = bi;
    }
    int cvr = __builtin_amdgcn_readfirstlane(cnt[bkt]);
    float ic = 1.0f / fmaxf((float)cvr, 1.0f);
    int cv = cvr > CAP ? CAP : cvr;

    const int* eb = ebuf + bkt * CAP;
    float acc[11];
    #pragma unroll
    for (int j = 0; j < 11; ++j) acc[j] = 0.f;

    for (int e = 0; e < cv; e += 4) {
        int4 q = *(const int4*)(eb + e);   // 16B-aligned (CAP*4 = 384)
        int m = cv - e;
        {
            int s0 = __builtin_amdgcn_readfirstlane(q.x);
            const float* p = in + (size_t)s0 * NBF;
            #pragma unroll
            for (int j = 0; j < 11; ++j) {
                float v = p[j * 64 + lane];
                if (LEAKY) v = v >= 0.f ? v : 0.01f * v;
                acc[j] += v;
            }
        }
        if (m > 1) {
            int s1 = __builtin_amdgcn_readfirstlane(q.y);
            const float* p = in + (size_t)s1 * NBF;
            #pragma unroll
            for (int j = 0; j < 11; ++j) {
                float v = p[j * 64 + lane];
                if (LEAKY) v = v >= 0.f ? v : 0.01f * v;
                acc[j] += v;
            }
        }
        if (m > 2) {
            int s2 = __builtin_amdgcn_readfirstlane(q.z);
            const float* p = in + (size_t)s2 * NBF;
            #pragma unroll
            for (int j = 0; j < 11; ++j) {
                float v = p[j * 64 + lane];
                if (LEAKY) v = v >= 0.f ? v : 0.01f * v;
                acc[j] += v;
            }
        }
        if (m > 3) {
            int s3 = __builtin_amdgcn_readfirstlane(q.w);
            const float* p = in + (size_t)s3 * NBF;
            #pragma unroll
            for (int j = 0; j < 11; ++j) {
                float v = p[j * 64 + lane];
                if (LEAKY) v = v >= 0.f ? v : 0.01f * v;
                acc[j] += v;
            }
        }
    }

    float* zp = z + (size_t)bi * NBF;
    #pragma unroll
    for (int j = 0; j < 11; ++j) zp[j * 64 + lane] = acc[j] * ic;
}

// ---------------- RGCN dense transform, k-split across 4 waves ----------------
// wave 0: self row @ root; waves 1-3: z slab r @ rel_r. A-slabs are wave-uniform
// (s_load); weight columns live in VGPRs; cross-wave reduce via LDS.
template<bool LEAKY, bool SEL, int NDST, bool TOUT>
__global__ __launch_bounds__(256) void k_xform(
    const float* __restrict__ in, const float* __restrict__ z,
    const float* __restrict__ root, const float* __restrict__ rel,
    const float* __restrict__ bias, const int* __restrict__ sel,
    float* __restrict__ out)
{
    __shared__ float sP[8][4][NFP];   // [row-in-chunk][wave][feature]

    int wave = __builtin_amdgcn_readfirstlane(threadIdx.x >> 6);
    int lane = threadIdx.x & 63;
    int rowbase = blockIdx.x * 16;

    const float* wbase = (wave == 0) ? root : (rel + (size_t)(wave - 1) * NF * NF);
    float wsl[43];
    #pragma unroll
    for (int j = 0; j < 43; ++j)
        wsl[j] = (lane < NF) ? wbase[j * NF + lane] : 0.f;

    for (int rr8 = 0; rr8 < 16; rr8 += 8) {
        #pragma unroll 1
        for (int rr = 0; rr < 8; ++rr) {
            int t = rowbase + rr8 + rr;
            int b = t / NDST, i = t - b * NDST;
            const float* arow;
            if (wave == 0) {
                int node = SEL ? sel[i] : i;
                arow = in + (size_t)node * NBF + b * NFP;
            } else {
                int zrow = (wave - 1) * NDST + i;
                arow = z + (size_t)zrow * NBF + b * NFP;
            }
            float a0 = 0.f, a1 = 0.f, a2 = 0.f, a3 = 0.f;
            #pragma unroll
            for (int j = 0; j < 40; j += 4) {
                float v0 = arow[j], v1 = arow[j + 1], v2 = arow[j + 2], v3 = arow[j + 3];
                if (LEAKY && wave == 0) {
                    v0 = v0 >= 0.f ? v0 : 0.01f * v0;
                    v1 = v1 >= 0.f ? v1 : 0.01f * v1;
                    v2 = v2 >= 0.f ? v2 : 0.01f * v2;
                    v3 = v3 >= 0.f ? v3 : 0.01f * v3;
                }
                a0 = fmaf(v0, wsl[j], a0);
                a1 = fmaf(v1, wsl[j + 1], a1);
                a2 = fmaf(v2, wsl[j + 2], a2);
                a3 = fmaf(v3, wsl[j + 3], a3);
            }
            {
                float v0 = arow[40], v1 = arow[41], v2 = arow[42];
                if (LEAKY && wave == 0) {
                    v0 = v0 >= 0.f ? v0 : 0.01f * v0;
                    v1 = v1 >= 0.f ? v1 : 0.01f * v1;
                    v2 = v2 >= 0.f ? v2 : 0.01f * v2;
                }
                a0 = fmaf(v0, wsl[40], a0);
                a1 = fmaf(v1, wsl[41], a1);
                a2 = fmaf(v2, wsl[42], a2);
            }
            if (lane < NF) sP[rr][wave][lane] = (a0 + a1) + (a2 + a3);
        }
        __syncthreads();
        if (lane < NF) {
            int r0 = 2 * wave, r1 = 2 * wave + 1;
            float bi_ = bias[lane];
            float s0 = ((sP[r0][0][lane] + sP[r0][1][lane]) +
                        (sP[r0][2][lane] + sP[r0][3][lane])) + bi_;
            float s1 = ((sP[r1][0][lane] + sP[r1][1][lane]) +
                        (sP[r1][2][lane] + sP[r1][3][lane])) + bi_;
            int t0 = rowbase + rr8 + r0, t1 = rowbase + rr8 + r1;
            if (TOUT) {
                int b0 = t0 / NDST, i0 = t0 - b0 * NDST;
                int b1 = t1 / NDST, i1 = t1 - b1 * NDST;
                out[(size_t)i0 * NBF + b0 * NFP + lane] = s0;
                out[(size_t)i1 * NBF + b1 * NFP + lane] = s1;
            } else {
                out[(size_t)t0 * NFP + lane] = s0;
                out[(size_t)t1 * NFP + lane] = s1;
            }
        }
        __syncthreads();
    }
}

// ---------------- epilogue: gather + 1x1 conv + softmax ----------------
__device__ inline float wred_max(float v) {
    #pragma unroll
    for (int o = 32; o > 0; o >>= 1) v = fmaxf(v, __shfl_down(v, o));
    return v;
}
__device__ inline float wred_sum(float v) {
    #pragma unroll
    for (int o = 32; o > 0; o >>= 1) v += __shfl_down(v, o);
    return v;
}

__global__ __launch_bounds__(512) void k_final(
    const float* __restrict__ x, const float* __restrict__ h2,
    const float* __restrict__ la, const int* __restrict__ nodes,
    const float* __restrict__ wf, const float* __restrict__ bf,
    float* __restrict__ out)
{
    __shared__ float sl[NS + 1];
    __shared__ float sred[8];
    __shared__ float sbc[2];
    int b = blockIdx.x, tid = threadIdx.x;

    if (tid < NS) {
        int node = nodes[tid];
        float acc = bf[0] + wf[0] * la[b * (NS + 1) + 1 + tid];
        const float* xp = x  + (size_t)node * NBF + b * NFP;   // transposed x
        const float* hp = h2 + ((size_t)b * NS + tid) * NFP;   // compact h2
        #pragma unroll
        for (int c = 0; c < NF; ++c) acc = fmaf(wf[1 + c], xp[c], acc);
        #pragma unroll
        for (int c = 0; c < NF; ++c) {
            float t = hp[c];
            t = t >= 0.f ? t : 0.01f * t;   // leaky relu on RGCN2 output
            acc = fmaf(wf[44 + c], t, acc);
        }
        sl[tid + 1] = acc;
    }
    if (tid == 0) sl[0] = 0.f;   // cash logit
    __syncthreads();

    float m = (tid < NS + 1) ? sl[tid] : -3.0e38f;
    m = wred_max(m);
    if ((tid & 63) == 0) sred[tid >> 6] = m;
    __syncthreads();
    if (tid == 0) {
        float mm = sred[0];
        #pragma unroll
        for (int i = 1; i < 8; ++i) mm = fmaxf(mm, sred[i]);
        sbc[0] = mm;
    }
    __syncthreads();
    float mx = sbc[0];
    float e = (tid < NS + 1) ? expf(sl[tid] - mx) : 0.f;
    float s = wred_sum(e);
    if ((tid & 63) == 0) sred[tid >> 6] = s;
    __syncthreads();
    if (tid == 0) {
        float t = 0.f;
        #pragma unroll
        for (int i = 0; i < 8; ++i) t += sred[i];
        sbc[1] = t;
    }
    __syncthreads();
    if (tid < NS + 1) out[(size_t)b * (NS + 1) + tid] = e / sbc[1];
}

extern "C" void kernel_launch(void* const* d_in, const int* in_sizes, int n_in,
                              void* d_out, int out_size, void* d_ws, size_t ws_size,
                              hipStream_t stream)
{
    const float* obs   = (const float*)d_in[0];
    const float* la    = (const float*)d_in[1];
    const int*   ei    = (const int*)d_in[2];
    const int*   et    = (const int*)d_in[3];
    const int*   nodes = (const int*)d_in[4];
    const float* ws1 = (const float*)d_in[5],  *bs1 = (const float*)d_in[6];
    const float* ws2 = (const float*)d_in[7],  *bs2 = (const float*)d_in[8];
    const float* wm1 = (const float*)d_in[9],  *bm1 = (const float*)d_in[10];
    const float* wm2 = (const float*)d_in[11], *bm2 = (const float*)d_in[12];
    const float* root1 = (const float*)d_in[13], *rel1 = (const float*)d_in[14], *bias1 = (const float*)d_in[15];
    const float* root2 = (const float*)d_in[16], *rel2 = (const float*)d_in[17], *bias2 = (const float*)d_in[18];
    const float* wf = (const float*)d_in[19], *bf = (const float*)d_in[20];

    float* wsp = (float*)d_ws;
    float* x   = wsp + XT_OFF;
    float* h1  = wsp + H1_OFF;
    float* z   = wsp + Z_OFF;
    float* h2  = wsp + H2_OFF;
    int*   ibase = (int*)(wsp + INT_BASE);
    int*   cnt   = ibase + CNT_OFF;
    int*   ebuf  = ibase + EBUF_OFF;

    hipMemsetAsync(cnt, 0, NBKT * sizeof(int), stream);

    // fused: temporal features (blocks 0..749) + bucket fill (blocks 750..1124)
    k_front<<<750 + NE / 256, 256, 0, stream>>>(
        obs, ws1, bs1, ws2, bs2, wm1, bm1, wm2, bm2, x, ei, et, cnt, ebuf);

    // RGCN layer 1: all 9000 buckets, all batches per wave
    k_aggregate<false, false><<<NBKT / 4, 256, 0, stream>>>(
        x, cnt, ebuf, nullptr, z, NBKT);
    k_xform<false, false, NN, true><<<NB * NN / 16, 256, 0, stream>>>(
        x, z, root1, rel1, bias1, nullptr, h1);

    // RGCN layer 2: 1500 buckets (3 rel x 500 selected dst)
    k_aggregate<true, true><<<(NR * NS) / 4, 256, 0, stream>>>(
        h1, cnt, ebuf, nodes, z, NR * NS);
    k_xform<true, true, NS, false><<<NB * NS / 16, 256, 0, stream>>>(
        h1, z, root2, rel2, bias2, nodes, h2);

    k_final<<<NB, 512, 0, stream>>>(x, h2, la, nodes, wf, bf, (float*)d_out);
}